// Round 1
// baseline (898.719 us; speedup 1.0000x reference)
//
#include <hip/hip_runtime.h>
#include <hip/hip_bf16.h>
#include <math.h>

#define N_NODES 50000
#define N_EDGES 500000
#define F_IN 64
#define F_OUT 64
#define C_DIM 128   // F_IN + F_OUT

// ---------------- graph preprocessing ----------------

__global__ void count_deg(const int* __restrict__ row, const int* __restrict__ col,
                          int* __restrict__ dout, int* __restrict__ din, int e) {
    int i = blockIdx.x * blockDim.x + threadIdx.x;
    if (i >= e) return;
    atomicAdd(&dout[row[i]], 1);
    atomicAdd(&din[col[i]], 1);
}

// exclusive scan of counts (deg_in) -> rowptr, per 1024-block
__global__ void scan_block(const int* __restrict__ counts, int* __restrict__ excl,
                           int* __restrict__ blocksums, int n) {
    __shared__ int tmp[1024];
    int tid = threadIdx.x;
    int gid = blockIdx.x * 1024 + tid;
    int v = (gid < n) ? counts[gid] : 0;
    tmp[tid] = v;
    __syncthreads();
    for (int off = 1; off < 1024; off <<= 1) {
        int t = (tid >= off) ? tmp[tid - off] : 0;
        __syncthreads();
        tmp[tid] += t;
        __syncthreads();
    }
    int incl = tmp[tid];
    if (gid < n) excl[gid] = incl - v;
    if (tid == 1023) blocksums[blockIdx.x] = incl;
}

__global__ void scan_sums(int* __restrict__ blocksums, int nb) {
    __shared__ int tmp[64];
    int tid = threadIdx.x;
    int v = (tid < nb) ? blocksums[tid] : 0;
    tmp[tid] = v;
    __syncthreads();
    for (int off = 1; off < 64; off <<= 1) {
        int t = (tid >= off) ? tmp[tid - off] : 0;
        __syncthreads();
        tmp[tid] += t;
        __syncthreads();
    }
    if (tid < nb) blocksums[tid] = tmp[tid] - v;  // exclusive offsets
}

__global__ void scan_add(int* __restrict__ rowptr, const int* __restrict__ blocksums,
                         int* __restrict__ cursor, int n, int e_total) {
    int gid = blockIdx.x * blockDim.x + threadIdx.x;
    if (gid < n) {
        int v = rowptr[gid] + blocksums[gid >> 10];
        rowptr[gid] = v;
        cursor[gid] = v;
    }
    if (gid == n) rowptr[n] = e_total;
}

__global__ void build_csr(const int* __restrict__ row, const int* __restrict__ col,
                          const int* __restrict__ dout, const int* __restrict__ din,
                          int* __restrict__ cursor, int* __restrict__ src,
                          float* __restrict__ wo, float* __restrict__ wi, int e) {
    int i = blockIdx.x * blockDim.x + threadIdx.x;
    if (i >= e) return;
    int r = row[i], c = col[i];
    int pos = atomicAdd(&cursor[c], 1);
    src[pos] = r;
    wo[pos] = 1.0f / (float)dout[r];
    wi[pos] = 1.0f / (float)din[r];
}

// ---------------- weight packing ----------------
// tensors order {Xc, T1o, T1i, T2o, T2i} -> weights {W[0,0]+W[1,0], W[0,1], W[1,1], W[0,2], W[1,2]}
// W layout (2,3,128,64): [d][kk][k][j] = ((d*3+kk)*128 + k)*64 + j

__device__ __forceinline__ float pick_w(const float* W, int t, int k, int j) {
    if (t == 0) return W[(0 * 3 + 0) * 128 * 64 + k * 64 + j] + W[(1 * 3 + 0) * 128 * 64 + k * 64 + j];
    int d = (t == 2 || t == 4) ? 1 : 0;
    int kk = (t <= 2) ? 1 : 2;
    return W[(d * 3 + kk) * 128 * 64 + k * 64 + j];
}

__global__ void pack_wzr(const float* __restrict__ Wz, const float* __restrict__ Wr,
                         float* __restrict__ Wbig) {  // [5][128][128], c<64 -> Z, c>=64 -> R
    int i = blockIdx.x * blockDim.x + threadIdx.x;
    if (i >= 5 * 128 * 128) return;
    int c = i & 127;
    int k = (i >> 7) & 127;
    int t = i >> 14;
    const float* W = (c < 64) ? Wz : Wr;
    Wbig[i] = pick_w(W, t, k, c & 63);
}

__global__ void pack_wh(const float* __restrict__ Wh, float* __restrict__ Wbig) {  // [5][128][64]
    int i = blockIdx.x * blockDim.x + threadIdx.x;
    if (i >= 5 * 128 * 64) return;
    int c = i & 63;
    int k = (i >> 6) & 127;
    int t = i >> 13;
    Wbig[i] = pick_w(Wh, t, k, c);
}

// ---------------- concat ----------------

__global__ void concat_xh(const float* __restrict__ X, const float* __restrict__ H,
                          float* __restrict__ XH, int n) {
    int i = blockIdx.x * blockDim.x + threadIdx.x;
    if (i >= n * C_DIM) return;
    int r = i >> 7, c = i & 127;
    XH[i] = (c < 64) ? X[r * 64 + c] : H[r * 64 + (c - 64)];
}

__global__ void concat_xhr(const float* __restrict__ X, const float* __restrict__ H,
                           const float* __restrict__ ZR, float* __restrict__ XHR, int n) {
    int i = blockIdx.x * blockDim.x + threadIdx.x;
    if (i >= n * C_DIM) return;
    int r = i >> 7, c = i & 127;
    XHR[i] = (c < 64) ? X[r * 64 + c] : H[r * 64 + (c - 64)] * ZR[i];  // ZR[r*128+c] holds R[c-64] for c>=64
}

// ---------------- diffusion props (pull-mode, one wave per node) ----------------

__global__ void prop1_kernel(const float* __restrict__ S,
                             const int* __restrict__ rowptr, const int* __restrict__ src,
                             const float* __restrict__ wo, const float* __restrict__ wi,
                             float* __restrict__ T1o, float* __restrict__ T1i, int n) {
    int wave = (blockIdx.x * blockDim.x + threadIdx.x) >> 6;
    int lane = threadIdx.x & 63;
    if (wave >= n) return;
    int beg = rowptr[wave], end = rowptr[wave + 1];
    float ao0 = 0.f, ao1 = 0.f, ai0 = 0.f, ai1 = 0.f;
    for (int j = beg; j < end; ++j) {
        int s = src[j];
        float w_o = wo[j], w_i = wi[j];
        float x0 = S[s * C_DIM + lane];
        float x1 = S[s * C_DIM + 64 + lane];
        ao0 += w_o * x0; ao1 += w_o * x1;
        ai0 += w_i * x0; ai1 += w_i * x1;
    }
    T1o[wave * C_DIM + lane] = ao0; T1o[wave * C_DIM + 64 + lane] = ao1;
    T1i[wave * C_DIM + lane] = ai0; T1i[wave * C_DIM + 64 + lane] = ai1;
}

__global__ void prop2_kernel(const float* __restrict__ T1o, const float* __restrict__ T1i,
                             const float* __restrict__ Xc,
                             const int* __restrict__ rowptr, const int* __restrict__ src,
                             const float* __restrict__ wo, const float* __restrict__ wi,
                             float* __restrict__ T2o, float* __restrict__ T2i, int n) {
    int wave = (blockIdx.x * blockDim.x + threadIdx.x) >> 6;
    int lane = threadIdx.x & 63;
    if (wave >= n) return;
    int beg = rowptr[wave], end = rowptr[wave + 1];
    float ao0 = 0.f, ao1 = 0.f, ai0 = 0.f, ai1 = 0.f;
    for (int j = beg; j < end; ++j) {
        int s = src[j];
        float w_o = wo[j], w_i = wi[j];
        ao0 += w_o * T1o[s * C_DIM + lane];
        ao1 += w_o * T1o[s * C_DIM + 64 + lane];
        ai0 += w_i * T1i[s * C_DIM + lane];
        ai1 += w_i * T1i[s * C_DIM + 64 + lane];
    }
    float x0 = Xc[wave * C_DIM + lane];
    float x1 = Xc[wave * C_DIM + 64 + lane];
    T2o[wave * C_DIM + lane] = 2.f * ao0 - x0;
    T2o[wave * C_DIM + 64 + lane] = 2.f * ao1 - x1;
    T2i[wave * C_DIM + lane] = 2.f * ai0 - x0;
    T2i[wave * C_DIM + 64 + lane] = 2.f * ai1 - x1;
}

// ---------------- fused GEMMs ----------------
// ZR GEMM: out[r, 0:64]=sigmoid(sum_t A_t[r,:]@Wz_t + bz), out[r,64:128] same with Wr
// tile: 32 rows x 128 cols, 256 threads, thread computes 2 rows x 8 cols (c = cc + 16*j)

__global__ __launch_bounds__(256) void gemm_zr(
    const float* __restrict__ XH, const float* __restrict__ T1o, const float* __restrict__ T1i,
    const float* __restrict__ T2o, const float* __restrict__ T2i,
    const float* __restrict__ Wbig, const float* __restrict__ bz, const float* __restrict__ br,
    float* __restrict__ ZR, int n) {
    __shared__ float As[32][65];
    __shared__ float Ws[64][128];
    const float* tensors[5] = {XH, T1o, T1i, T2o, T2i};
    int tid = threadIdx.x;
    int rr = tid >> 4;       // 0..15 -> row pair
    int cc = tid & 15;       // 0..15
    int rowbase = blockIdx.x * 32;
    float acc[2][8];
#pragma unroll
    for (int a = 0; a < 2; ++a)
#pragma unroll
        for (int b = 0; b < 8; ++b) acc[a][b] = 0.f;

    for (int q = 0; q < 10; ++q) {
        int t = q >> 1;
        int h = (q & 1) * 64;
        const float* A = tensors[t];
        for (int i = tid; i < 32 * 64; i += 256) {
            int ar = i >> 6, ak = i & 63;
            int grow = rowbase + ar;
            As[ar][ak] = (grow < n) ? A[grow * C_DIM + h + ak] : 0.f;
        }
        const float* Wc = Wbig + (t * 128 + h) * 128;
        for (int i = tid; i < 64 * 128; i += 256) {
            (&Ws[0][0])[i] = Wc[i];
        }
        __syncthreads();
        for (int kk = 0; kk < 64; ++kk) {
            float a0 = As[rr * 2][kk];
            float a1 = As[rr * 2 + 1][kk];
#pragma unroll
            for (int j = 0; j < 8; ++j) {
                float w = Ws[kk][cc + 16 * j];
                acc[0][j] += a0 * w;
                acc[1][j] += a1 * w;
            }
        }
        __syncthreads();
    }
#pragma unroll
    for (int rl = 0; rl < 2; ++rl) {
        int r = rowbase + rr * 2 + rl;
        if (r >= n) continue;
#pragma unroll
        for (int j = 0; j < 8; ++j) {
            int c = cc + 16 * j;
            float bias = (c < 64) ? bz[c] : br[c - 64];
            float v = acc[rl][j] + bias;
            ZR[r * C_DIM + c] = 1.f / (1.f + expf(-v));
        }
    }
}

// H GEMM + fused GRU epilogue: out = z*h + (1-z)*tanh(gemm + bh)
// tile: 32 rows x 64 cols, 256 threads, thread computes 2 rows x 4 cols (c = cc + 16*j)

__global__ __launch_bounds__(256) void gemm_h(
    const float* __restrict__ XHR, const float* __restrict__ T1o, const float* __restrict__ T1i,
    const float* __restrict__ T2o, const float* __restrict__ T2i,
    const float* __restrict__ Wbig, const float* __restrict__ bh,
    const float* __restrict__ ZR, const float* __restrict__ H,
    float* __restrict__ out, int n) {
    __shared__ float As[32][65];
    __shared__ float Ws[64][64];
    const float* tensors[5] = {XHR, T1o, T1i, T2o, T2i};
    int tid = threadIdx.x;
    int rr = tid >> 4;
    int cc = tid & 15;
    int rowbase = blockIdx.x * 32;
    float acc[2][4];
#pragma unroll
    for (int a = 0; a < 2; ++a)
#pragma unroll
        for (int b = 0; b < 4; ++b) acc[a][b] = 0.f;

    for (int q = 0; q < 10; ++q) {
        int t = q >> 1;
        int h = (q & 1) * 64;
        const float* A = tensors[t];
        for (int i = tid; i < 32 * 64; i += 256) {
            int ar = i >> 6, ak = i & 63;
            int grow = rowbase + ar;
            As[ar][ak] = (grow < n) ? A[grow * C_DIM + h + ak] : 0.f;
        }
        const float* Wc = Wbig + (t * 128 + h) * 64;
        for (int i = tid; i < 64 * 64; i += 256) {
            (&Ws[0][0])[i] = Wc[i];
        }
        __syncthreads();
        for (int kk = 0; kk < 64; ++kk) {
            float a0 = As[rr * 2][kk];
            float a1 = As[rr * 2 + 1][kk];
#pragma unroll
            for (int j = 0; j < 4; ++j) {
                float w = Ws[kk][cc + 16 * j];
                acc[0][j] += a0 * w;
                acc[1][j] += a1 * w;
            }
        }
        __syncthreads();
    }
#pragma unroll
    for (int rl = 0; rl < 2; ++rl) {
        int r = rowbase + rr * 2 + rl;
        if (r >= n) continue;
#pragma unroll
        for (int j = 0; j < 4; ++j) {
            int c = cc + 16 * j;
            float ht = tanhf(acc[rl][j] + bh[c]);
            float z = ZR[r * C_DIM + c];
            float h_old = H[r * 64 + c];
            out[r * 64 + c] = z * h_old + (1.f - z) * ht;
        }
    }
}

// ---------------- launch ----------------

static inline size_t roundup64(size_t x) { return (x + 63) & ~(size_t)63; }

extern "C" void kernel_launch(void* const* d_in, const int* in_sizes, int n_in,
                              void* d_out, int out_size, void* d_ws, size_t ws_size,
                              hipStream_t stream) {
    const float* X  = (const float*)d_in[0];
    const int*   EI = (const int*)d_in[1];
    const float* H  = (const float*)d_in[2];
    const float* Wz = (const float*)d_in[3];
    const float* bz = (const float*)d_in[4];
    const float* Wr = (const float*)d_in[5];
    const float* br = (const float*)d_in[6];
    const float* Wh = (const float*)d_in[7];
    const float* bh = (const float*)d_in[8];
    float* out = (float*)d_out;

    const int* row = EI;
    const int* col = EI + N_EDGES;

    // workspace carve (elements are 4 bytes each)
    char* ws = (char*)d_ws;
    size_t off = 0;
    auto carve = [&](size_t elems) {
        void* p = ws + off;
        off += roundup64(elems * 4);
        return p;
    };
    int*   deg_out   = (int*)carve(N_NODES);
    int*   deg_in    = (int*)carve(N_NODES);
    int*   rowptr    = (int*)carve(N_NODES + 1);
    int*   cursor    = (int*)carve(N_NODES);
    int*   blocksums = (int*)carve(64);
    int*   csr_src   = (int*)carve(N_EDGES);
    float* csr_wo    = (float*)carve(N_EDGES);
    float* csr_wi    = (float*)carve(N_EDGES);
    float* XH        = (float*)carve((size_t)N_NODES * C_DIM);
    float* T1o       = (float*)carve((size_t)N_NODES * C_DIM);
    float* T1i       = (float*)carve((size_t)N_NODES * C_DIM);
    float* T2o       = (float*)carve((size_t)N_NODES * C_DIM);
    float* T2i       = (float*)carve((size_t)N_NODES * C_DIM);
    float* ZR        = (float*)carve((size_t)N_NODES * C_DIM);
    float* Wbig_zr   = (float*)carve(5 * 128 * 128);
    float* Wbig_h    = (float*)carve(5 * 128 * 64);

    // 1. zero degree arrays (deg_out and deg_in are adjacent)
    hipMemsetAsync(deg_out, 0, roundup64(N_NODES * 4) + roundup64(N_NODES * 4), stream);

    // 2. degrees
    count_deg<<<(N_EDGES + 255) / 256, 256, 0, stream>>>(row, col, deg_out, deg_in, N_EDGES);

    // 3. exclusive scan of deg_in -> rowptr
    int nblk = (N_NODES + 1023) / 1024;  // 49
    scan_block<<<nblk, 1024, 0, stream>>>(deg_in, rowptr, blocksums, N_NODES);
    scan_sums<<<1, 64, 0, stream>>>(blocksums, nblk);
    scan_add<<<(N_NODES + 1 + 255) / 256, 256, 0, stream>>>(rowptr, blocksums, cursor, N_NODES, N_EDGES);

    // 4. CSR build with per-edge weights
    build_csr<<<(N_EDGES + 255) / 256, 256, 0, stream>>>(row, col, deg_out, deg_in,
                                                         cursor, csr_src, csr_wo, csr_wi, N_EDGES);

    // 5. pack weights
    pack_wzr<<<(5 * 128 * 128 + 255) / 256, 256, 0, stream>>>(Wz, Wr, Wbig_zr);
    pack_wh<<<(5 * 128 * 64 + 255) / 256, 256, 0, stream>>>(Wh, Wbig_h);

    // 6. XH = [X, H]
    concat_xh<<<(N_NODES * C_DIM + 255) / 256, 256, 0, stream>>>(X, H, XH, N_NODES);

    // 7. props for Z/R (shared Chebyshev tensors)
    int prop_blocks = (N_NODES + 3) / 4;  // 4 waves per 256-thread block
    prop1_kernel<<<prop_blocks, 256, 0, stream>>>(XH, rowptr, csr_src, csr_wo, csr_wi, T1o, T1i, N_NODES);
    prop2_kernel<<<prop_blocks, 256, 0, stream>>>(T1o, T1i, XH, rowptr, csr_src, csr_wo, csr_wi, T2o, T2i, N_NODES);

    // 8. Z|R gemm
    int gemm_blocks = (N_NODES + 31) / 32;
    gemm_zr<<<gemm_blocks, 256, 0, stream>>>(XH, T1o, T1i, T2o, T2i, Wbig_zr, bz, br, ZR, N_NODES);

    // 9. XHR = [X, H*R] (overwrites XH; X,H inputs still pristine)
    concat_xhr<<<(N_NODES * C_DIM + 255) / 256, 256, 0, stream>>>(X, H, ZR, XH, N_NODES);

    // 10. props for H~
    prop1_kernel<<<prop_blocks, 256, 0, stream>>>(XH, rowptr, csr_src, csr_wo, csr_wi, T1o, T1i, N_NODES);
    prop2_kernel<<<prop_blocks, 256, 0, stream>>>(T1o, T1i, XH, rowptr, csr_src, csr_wo, csr_wi, T2o, T2i, N_NODES);

    // 11. H~ gemm + fused GRU mix -> out
    gemm_h<<<gemm_blocks, 256, 0, stream>>>(XH, T1o, T1i, T2o, T2i, Wbig_h, bh, ZR, H, out, N_NODES);
}

// Round 2
// 515.860 us; speedup vs baseline: 1.7422x; 1.7422x over previous
//
#include <hip/hip_runtime.h>
#include <hip/hip_bf16.h>
#include <math.h>

#define N_NODES 50000
#define N_EDGES 500000
#define C_DIM 128

typedef __attribute__((ext_vector_type(8))) short bf8;
typedef __attribute__((ext_vector_type(4))) float f32x4;

__device__ __forceinline__ float bfu2f(unsigned short u) {
    return __uint_as_float(((unsigned)u) << 16);
}
__device__ __forceinline__ unsigned short f2bfu(float f) {
    __hip_bfloat16 h = __float2bfloat16(f);
    unsigned short u;
    __builtin_memcpy(&u, &h, 2);
    return u;
}

// ---------------- graph preprocessing ----------------

__global__ void count_deg(const int* __restrict__ row, const int* __restrict__ col,
                          int* __restrict__ dout, int* __restrict__ din, int e) {
    int i = blockIdx.x * blockDim.x + threadIdx.x;
    if (i >= e) return;
    atomicAdd(&dout[row[i]], 1);
    atomicAdd(&din[col[i]], 1);
}

__global__ void scan_block(const int* __restrict__ counts, int* __restrict__ excl,
                           int* __restrict__ blocksums, int n) {
    __shared__ int tmp[1024];
    int tid = threadIdx.x;
    int gid = blockIdx.x * 1024 + tid;
    int v = (gid < n) ? counts[gid] : 0;
    tmp[tid] = v;
    __syncthreads();
    for (int off = 1; off < 1024; off <<= 1) {
        int t = (tid >= off) ? tmp[tid - off] : 0;
        __syncthreads();
        tmp[tid] += t;
        __syncthreads();
    }
    int incl = tmp[tid];
    if (gid < n) excl[gid] = incl - v;
    if (tid == 1023) blocksums[blockIdx.x] = incl;
}

__global__ void scan_sums(int* __restrict__ blocksums, int nb) {
    __shared__ int tmp[64];
    int tid = threadIdx.x;
    int v = (tid < nb) ? blocksums[tid] : 0;
    tmp[tid] = v;
    __syncthreads();
    for (int off = 1; off < 64; off <<= 1) {
        int t = (tid >= off) ? tmp[tid - off] : 0;
        __syncthreads();
        tmp[tid] += t;
        __syncthreads();
    }
    if (tid < nb) blocksums[tid] = tmp[tid] - v;
}

__global__ void scan_add(int* __restrict__ rowptr, const int* __restrict__ blocksums,
                         int* __restrict__ cursor, int n, int e_total) {
    int gid = blockIdx.x * blockDim.x + threadIdx.x;
    if (gid < n) {
        int v = rowptr[gid] + blocksums[gid >> 10];
        rowptr[gid] = v;
        cursor[gid] = v;
    }
    if (gid == n) rowptr[n] = e_total;
}

__global__ void build_csr(const int* __restrict__ row, const int* __restrict__ col,
                          const int* __restrict__ dout, const int* __restrict__ din,
                          int* __restrict__ cursor, int* __restrict__ src,
                          float2* __restrict__ w, int e) {
    int i = blockIdx.x * blockDim.x + threadIdx.x;
    if (i >= e) return;
    int r = row[i], c = col[i];
    int pos = atomicAdd(&cursor[c], 1);
    src[pos] = r;
    w[pos] = make_float2(1.0f / (float)dout[r], 1.0f / (float)din[r]);
}

// ---------------- weight packing (transposed [t][n][k], bf16) ----------------
// tensor slots t: {Xc, T1o, T1i, T2o, T2i} <- {W[0,0]+W[1,0], W[0,1], W[1,1], W[0,2], W[1,2]}
// raw W layout (2,3,128,64): [d][kk][k][j]

__device__ __forceinline__ float pick_w(const float* W, int t, int k, int j) {
    if (t == 0) return W[k * 64 + j] + W[3 * 128 * 64 + k * 64 + j];
    int d = (t == 2 || t == 4) ? 1 : 0;
    int kk = (t <= 2) ? 1 : 2;
    return W[(d * 3 + kk) * 128 * 64 + k * 64 + j];
}

__global__ void pack_wzr(const float* __restrict__ Wz, const float* __restrict__ Wr,
                         unsigned short* __restrict__ Wt) {  // [5][128 n][128 k]
    int i = blockIdx.x * blockDim.x + threadIdx.x;
    if (i >= 5 * 128 * 128) return;
    int k = i & 127;
    int nn = (i >> 7) & 127;
    int t = i >> 14;
    const float* W = (nn < 64) ? Wz : Wr;
    Wt[i] = f2bfu(pick_w(W, t, k, nn & 63));
}

__global__ void pack_wh(const float* __restrict__ Wh, unsigned short* __restrict__ Wt) {  // [5][64 n][128 k]
    int i = blockIdx.x * blockDim.x + threadIdx.x;
    if (i >= 5 * 64 * 128) return;
    int k = i & 127;
    int nn = (i >> 7) & 63;
    int t = i >> 13;
    Wt[i] = f2bfu(pick_w(Wh, t, k, nn));
}

// ---------------- concats (bf16 outputs) ----------------

__global__ void concat_xh(const float* __restrict__ X, const float* __restrict__ H,
                          unsigned short* __restrict__ XH, int n) {
    int i = blockIdx.x * blockDim.x + threadIdx.x;
    if (i >= n * C_DIM) return;
    int r = i >> 7, c = i & 127;
    float v = (c < 64) ? X[r * 64 + c] : H[r * 64 + (c - 64)];
    XH[i] = f2bfu(v);
}

// HR = H * R, elementwise [n][64]
__global__ void concat_hr(const float* __restrict__ H, const unsigned short* __restrict__ Rb,
                          unsigned short* __restrict__ HR, int n) {
    int i = blockIdx.x * blockDim.x + threadIdx.x;
    if (i >= n * 64) return;
    HR[i] = f2bfu(H[i] * bfu2f(Rb[i]));
}

// ---------------- diffusion props (pull-mode, one wave per node, bf16 rows) --

__global__ void prop1_128(const unsigned short* __restrict__ S,
                          const int* __restrict__ rowptr, const int* __restrict__ src,
                          const float2* __restrict__ w,
                          unsigned short* __restrict__ To, unsigned short* __restrict__ Ti, int n) {
    int node = (blockIdx.x * blockDim.x + threadIdx.x) >> 6;
    int lane = threadIdx.x & 63;
    if (node >= n) return;
    int beg = rowptr[node], end = rowptr[node + 1];
    float ao0 = 0.f, ao1 = 0.f, ai0 = 0.f, ai1 = 0.f;
    for (int j = beg; j < end; ++j) {
        int s = src[j];
        float2 wv = w[j];
        unsigned u = *(const unsigned*)(S + s * 128 + 2 * lane);
        float x0 = __uint_as_float(u << 16);
        float x1 = __uint_as_float(u & 0xffff0000u);
        ao0 = fmaf(wv.x, x0, ao0); ao1 = fmaf(wv.x, x1, ao1);
        ai0 = fmaf(wv.y, x0, ai0); ai1 = fmaf(wv.y, x1, ai1);
    }
    *(unsigned*)(To + node * 128 + 2 * lane) = ((unsigned)f2bfu(ao1) << 16) | f2bfu(ao0);
    *(unsigned*)(Ti + node * 128 + 2 * lane) = ((unsigned)f2bfu(ai1) << 16) | f2bfu(ai0);
}

__global__ void prop2_128(const unsigned short* __restrict__ T1o, const unsigned short* __restrict__ T1i,
                          const unsigned short* __restrict__ Xc,
                          const int* __restrict__ rowptr, const int* __restrict__ src,
                          const float2* __restrict__ w,
                          unsigned short* __restrict__ T2o, unsigned short* __restrict__ T2i, int n) {
    int node = (blockIdx.x * blockDim.x + threadIdx.x) >> 6;
    int lane = threadIdx.x & 63;
    if (node >= n) return;
    int beg = rowptr[node], end = rowptr[node + 1];
    float ao0 = 0.f, ao1 = 0.f, ai0 = 0.f, ai1 = 0.f;
    for (int j = beg; j < end; ++j) {
        int s = src[j];
        float2 wv = w[j];
        unsigned uo = *(const unsigned*)(T1o + s * 128 + 2 * lane);
        unsigned ui = *(const unsigned*)(T1i + s * 128 + 2 * lane);
        ao0 = fmaf(wv.x, __uint_as_float(uo << 16), ao0);
        ao1 = fmaf(wv.x, __uint_as_float(uo & 0xffff0000u), ao1);
        ai0 = fmaf(wv.y, __uint_as_float(ui << 16), ai0);
        ai1 = fmaf(wv.y, __uint_as_float(ui & 0xffff0000u), ai1);
    }
    unsigned ux = *(const unsigned*)(Xc + node * 128 + 2 * lane);
    float x0 = __uint_as_float(ux << 16);
    float x1 = __uint_as_float(ux & 0xffff0000u);
    *(unsigned*)(T2o + node * 128 + 2 * lane) =
        ((unsigned)f2bfu(2.f * ao1 - x1) << 16) | f2bfu(2.f * ao0 - x0);
    *(unsigned*)(T2i + node * 128 + 2 * lane) =
        ((unsigned)f2bfu(2.f * ai1 - x1) << 16) | f2bfu(2.f * ai0 - x0);
}

__global__ void prop1_64(const unsigned short* __restrict__ S,
                         const int* __restrict__ rowptr, const int* __restrict__ src,
                         const float2* __restrict__ w,
                         unsigned short* __restrict__ To, unsigned short* __restrict__ Ti, int n) {
    int node = (blockIdx.x * blockDim.x + threadIdx.x) >> 6;
    int lane = threadIdx.x & 63;
    if (node >= n) return;
    int beg = rowptr[node], end = rowptr[node + 1];
    float ao = 0.f, ai = 0.f;
    for (int j = beg; j < end; ++j) {
        int s = src[j];
        float2 wv = w[j];
        float x = bfu2f(S[s * 64 + lane]);
        ao = fmaf(wv.x, x, ao);
        ai = fmaf(wv.y, x, ai);
    }
    To[node * 64 + lane] = f2bfu(ao);
    Ti[node * 64 + lane] = f2bfu(ai);
}

__global__ void prop2_64(const unsigned short* __restrict__ U1o, const unsigned short* __restrict__ U1i,
                         const unsigned short* __restrict__ Xc,
                         const int* __restrict__ rowptr, const int* __restrict__ src,
                         const float2* __restrict__ w,
                         unsigned short* __restrict__ U2o, unsigned short* __restrict__ U2i, int n) {
    int node = (blockIdx.x * blockDim.x + threadIdx.x) >> 6;
    int lane = threadIdx.x & 63;
    if (node >= n) return;
    int beg = rowptr[node], end = rowptr[node + 1];
    float ao = 0.f, ai = 0.f;
    for (int j = beg; j < end; ++j) {
        int s = src[j];
        float2 wv = w[j];
        ao = fmaf(wv.x, bfu2f(U1o[s * 64 + lane]), ao);
        ai = fmaf(wv.y, bfu2f(U1i[s * 64 + lane]), ai);
    }
    float x = bfu2f(Xc[node * 64 + lane]);
    U2o[node * 64 + lane] = f2bfu(2.f * ao - x);
    U2i[node * 64 + lane] = f2bfu(2.f * ai - x);
}

// ---------------- MFMA GEMMs ----------------
// mfma_f32_16x16x32_bf16 layouts (guide-verified):
//   A frag: A[m = lane&15][k = (lane>>4)*8 + j], j=0..7  (8 contiguous bf16 along k)
//   B frag: B[k = (lane>>4)*8 + j][n = lane&15]          (load from [n][k]-transposed W)
//   C/D:    col = lane&15, row = (lane>>4)*4 + reg

// ZR: [n,640]@[640,128], K = 5 tensors x 128. Wave: 32 rows (2 m-tiles) x full N=128.
__global__ __launch_bounds__(256) void gemm_zr_mfma(
    const unsigned short* __restrict__ XH, const unsigned short* __restrict__ T1o,
    const unsigned short* __restrict__ T1i, const unsigned short* __restrict__ T2o,
    const unsigned short* __restrict__ T2i,
    const unsigned short* __restrict__ Wt,  // [5][128][128]
    const float* __restrict__ bz, const float* __restrict__ br,
    float* __restrict__ Zf, unsigned short* __restrict__ Rb, int n) {
    int lane = threadIdx.x & 63;
    int wave = blockIdx.x * 4 + (threadIdx.x >> 6);
    int rowbase = wave * 32;
    if (rowbase >= n) return;
    int lr = lane & 15;
    int quad = lane >> 4;
    int r0 = rowbase + lr;       if (r0 >= n) r0 = n - 1;
    int r1 = rowbase + 16 + lr;  if (r1 >= n) r1 = n - 1;

    f32x4 zero = {0.f, 0.f, 0.f, 0.f};
    f32x4 acc[2][8];
#pragma unroll
    for (int a = 0; a < 2; ++a)
#pragma unroll
        for (int b = 0; b < 8; ++b) acc[a][b] = zero;

    const unsigned short* tensors[5] = {XH, T1o, T1i, T2o, T2i};
#pragma unroll
    for (int t = 0; t < 5; ++t) {
        const unsigned short* A = tensors[t];
        const unsigned short* Ab0 = A + (size_t)r0 * 128 + quad * 8;
        const unsigned short* Ab1 = A + (size_t)r1 * 128 + quad * 8;
        const unsigned short* Wb = Wt + (size_t)t * 128 * 128 + lr * 128 + quad * 8;
#pragma unroll
        for (int kk = 0; kk < 4; ++kk) {
            bf8 a0 = *(const bf8*)(Ab0 + kk * 32);
            bf8 a1 = *(const bf8*)(Ab1 + kk * 32);
#pragma unroll
            for (int nt = 0; nt < 8; ++nt) {
                bf8 b = *(const bf8*)(Wb + nt * 16 * 128 + kk * 32);
                acc[0][nt] = __builtin_amdgcn_mfma_f32_16x16x32_bf16(a0, b, acc[0][nt], 0, 0, 0);
                acc[1][nt] = __builtin_amdgcn_mfma_f32_16x16x32_bf16(a1, b, acc[1][nt], 0, 0, 0);
            }
        }
    }
#pragma unroll
    for (int mt = 0; mt < 2; ++mt)
#pragma unroll
        for (int reg = 0; reg < 4; ++reg) {
            int r = rowbase + mt * 16 + quad * 4 + reg;
            if (r >= n) continue;
#pragma unroll
            for (int nt = 0; nt < 8; ++nt) {
                int c = nt * 16 + lr;
                float bias = (c < 64) ? bz[c] : br[c - 64];
                float v = acc[mt][nt][reg] + bias;
                float s = 1.f / (1.f + expf(-v));
                if (nt < 4) Zf[(size_t)r * 64 + c] = s;
                else        Rb[(size_t)r * 64 + (c - 64)] = f2bfu(s);
            }
        }
}

// H~: [n,640]@[640,64] + GRU epilogue. K segments: per tensor t, k<64 from X-side
// (cols 0-63 of XH-based tensors), k>=64 from U tensors (H*R props).
__global__ __launch_bounds__(256) void gemm_h_mfma(
    const unsigned short* __restrict__ XH, const unsigned short* __restrict__ T1o,
    const unsigned short* __restrict__ T1i, const unsigned short* __restrict__ T2o,
    const unsigned short* __restrict__ T2i,
    const unsigned short* __restrict__ HR, const unsigned short* __restrict__ U1o,
    const unsigned short* __restrict__ U1i, const unsigned short* __restrict__ U2o,
    const unsigned short* __restrict__ U2i,
    const unsigned short* __restrict__ Wt,  // [5][64][128]
    const float* __restrict__ bh, const float* __restrict__ Zf,
    const float* __restrict__ H, float* __restrict__ out, int n) {
    int lane = threadIdx.x & 63;
    int wave = blockIdx.x * 4 + (threadIdx.x >> 6);
    int rowbase = wave * 32;
    if (rowbase >= n) return;
    int lr = lane & 15;
    int quad = lane >> 4;
    int r0 = rowbase + lr;       if (r0 >= n) r0 = n - 1;
    int r1 = rowbase + 16 + lr;  if (r1 >= n) r1 = n - 1;

    f32x4 zero = {0.f, 0.f, 0.f, 0.f};
    f32x4 acc[2][4];
#pragma unroll
    for (int a = 0; a < 2; ++a)
#pragma unroll
        for (int b = 0; b < 4; ++b) acc[a][b] = zero;

    const unsigned short* tX[5] = {XH, T1o, T1i, T2o, T2i};  // stride 128, cols 0-63
    const unsigned short* tU[5] = {HR, U1o, U1i, U2o, U2i};  // stride 64
#pragma unroll
    for (int t = 0; t < 5; ++t) {
        const unsigned short* Wb = Wt + (size_t)t * 64 * 128 + lr * 128 + quad * 8;
#pragma unroll
        for (int kk = 0; kk < 4; ++kk) {
            bf8 a0, a1;
            if (kk < 2) {
                const unsigned short* A = tX[t];
                a0 = *(const bf8*)(A + (size_t)r0 * 128 + kk * 32 + quad * 8);
                a1 = *(const bf8*)(A + (size_t)r1 * 128 + kk * 32 + quad * 8);
            } else {
                const unsigned short* A = tU[t];
                a0 = *(const bf8*)(A + (size_t)r0 * 64 + (kk - 2) * 32 + quad * 8);
                a1 = *(const bf8*)(A + (size_t)r1 * 64 + (kk - 2) * 32 + quad * 8);
            }
#pragma unroll
            for (int nt = 0; nt < 4; ++nt) {
                bf8 b = *(const bf8*)(Wb + nt * 16 * 128 + kk * 32);
                acc[0][nt] = __builtin_amdgcn_mfma_f32_16x16x32_bf16(a0, b, acc[0][nt], 0, 0, 0);
                acc[1][nt] = __builtin_amdgcn_mfma_f32_16x16x32_bf16(a1, b, acc[1][nt], 0, 0, 0);
            }
        }
    }
#pragma unroll
    for (int mt = 0; mt < 2; ++mt)
#pragma unroll
        for (int reg = 0; reg < 4; ++reg) {
            int r = rowbase + mt * 16 + quad * 4 + reg;
            if (r >= n) continue;
#pragma unroll
            for (int nt = 0; nt < 4; ++nt) {
                int c = nt * 16 + lr;
                float ht = tanhf(acc[mt][nt][reg] + bh[c]);
                float z = Zf[(size_t)r * 64 + c];
                float h_old = H[(size_t)r * 64 + c];
                out[(size_t)r * 64 + c] = z * h_old + (1.f - z) * ht;
            }
        }
}

// ---------------- launch ----------------

static inline size_t rup(size_t x) { return (x + 63) & ~(size_t)63; }

extern "C" void kernel_launch(void* const* d_in, const int* in_sizes, int n_in,
                              void* d_out, int out_size, void* d_ws, size_t ws_size,
                              hipStream_t stream) {
    const float* X  = (const float*)d_in[0];
    const int*   EI = (const int*)d_in[1];
    const float* H  = (const float*)d_in[2];
    const float* Wz = (const float*)d_in[3];
    const float* bz = (const float*)d_in[4];
    const float* Wr = (const float*)d_in[5];
    const float* br = (const float*)d_in[6];
    const float* Wh = (const float*)d_in[7];
    const float* bh = (const float*)d_in[8];
    float* out = (float*)d_out;

    const int* row = EI;
    const int* col = EI + N_EDGES;

    char* ws = (char*)d_ws;
    size_t off = 0;
    auto carve = [&](size_t bytes) { void* p = ws + off; off += rup(bytes); return p; };

    int*   deg_out   = (int*)carve(N_NODES * 4);
    int*   deg_in    = (int*)carve(N_NODES * 4);
    int*   rowptr    = (int*)carve((N_NODES + 1) * 4);
    int*   cursor    = (int*)carve(N_NODES * 4);
    int*   blocksums = (int*)carve(64 * 4);
    int*   csr_src   = (int*)carve(N_EDGES * 4);
    float2* csr_w    = (float2*)carve(N_EDGES * 8);
    unsigned short* XH  = (unsigned short*)carve((size_t)N_NODES * 128 * 2);
    unsigned short* T1o = (unsigned short*)carve((size_t)N_NODES * 128 * 2);
    unsigned short* T1i = (unsigned short*)carve((size_t)N_NODES * 128 * 2);
    unsigned short* T2o = (unsigned short*)carve((size_t)N_NODES * 128 * 2);
    unsigned short* T2i = (unsigned short*)carve((size_t)N_NODES * 128 * 2);
    unsigned short* HR  = (unsigned short*)carve((size_t)N_NODES * 64 * 2);
    unsigned short* U1o = (unsigned short*)carve((size_t)N_NODES * 64 * 2);
    unsigned short* U1i = (unsigned short*)carve((size_t)N_NODES * 64 * 2);
    unsigned short* U2o = (unsigned short*)carve((size_t)N_NODES * 64 * 2);
    unsigned short* U2i = (unsigned short*)carve((size_t)N_NODES * 64 * 2);
    unsigned short* Rb  = (unsigned short*)carve((size_t)N_NODES * 64 * 2);
    float* Zf           = (float*)carve((size_t)N_NODES * 64 * 4);
    unsigned short* Wbig_zr = (unsigned short*)carve(5 * 128 * 128 * 2);
    unsigned short* Wbig_h  = (unsigned short*)carve(5 * 64 * 128 * 2);

    // degrees
    hipMemsetAsync(deg_out, 0, rup(N_NODES * 4) + rup(N_NODES * 4), stream);
    count_deg<<<(N_EDGES + 255) / 256, 256, 0, stream>>>(row, col, deg_out, deg_in, N_EDGES);

    // exclusive scan deg_in -> rowptr
    int nblk = (N_NODES + 1023) / 1024;
    scan_block<<<nblk, 1024, 0, stream>>>(deg_in, rowptr, blocksums, N_NODES);
    scan_sums<<<1, 64, 0, stream>>>(blocksums, nblk);
    scan_add<<<(N_NODES + 1 + 255) / 256, 256, 0, stream>>>(rowptr, blocksums, cursor, N_NODES, N_EDGES);

    // CSR by destination
    build_csr<<<(N_EDGES + 255) / 256, 256, 0, stream>>>(row, col, deg_out, deg_in,
                                                         cursor, csr_src, csr_w, N_EDGES);

    // weights
    pack_wzr<<<(5 * 128 * 128 + 255) / 256, 256, 0, stream>>>(Wz, Wr, Wbig_zr);
    pack_wh<<<(5 * 64 * 128 + 255) / 256, 256, 0, stream>>>(Wh, Wbig_h);

    // XH = [X, H] bf16
    concat_xh<<<(N_NODES * C_DIM + 255) / 256, 256, 0, stream>>>(X, H, XH, N_NODES);

    // props on XH (128 cols: X-part shared with H~ DConv)
    int prop_blocks = (N_NODES + 3) / 4;
    prop1_128<<<prop_blocks, 256, 0, stream>>>(XH, rowptr, csr_src, csr_w, T1o, T1i, N_NODES);
    prop2_128<<<prop_blocks, 256, 0, stream>>>(T1o, T1i, XH, rowptr, csr_src, csr_w, T2o, T2i, N_NODES);

    // Z|R GEMM (MFMA) -> Zf (fp32), Rb (bf16)
    int gemm_blocks = (N_NODES + 127) / 128;  // 4 waves/block, 32 rows/wave
    gemm_zr_mfma<<<gemm_blocks, 256, 0, stream>>>(XH, T1o, T1i, T2o, T2i, Wbig_zr, bz, br, Zf, Rb, N_NODES);

    // HR = H * R (64 cols), props on HR only
    concat_hr<<<(N_NODES * 64 + 255) / 256, 256, 0, stream>>>(H, Rb, HR, N_NODES);
    prop1_64<<<prop_blocks, 256, 0, stream>>>(HR, rowptr, csr_src, csr_w, U1o, U1i, N_NODES);
    prop2_64<<<prop_blocks, 256, 0, stream>>>(U1o, U1i, HR, rowptr, csr_src, csr_w, U2o, U2i, N_NODES);

    // H~ GEMM (MFMA) + GRU mix -> out (fp32)
    gemm_h_mfma<<<gemm_blocks, 256, 0, stream>>>(XH, T1o, T1i, T2o, T2i,
                                                 HR, U1o, U1i, U2o, U2i,
                                                 Wbig_h, bh, Zf, H, out, N_NODES);
}

// Round 3
// 400.448 us; speedup vs baseline: 2.2443x; 1.2882x over previous
//
#include <hip/hip_runtime.h>
#include <hip/hip_bf16.h>
#include <math.h>

#define N_NODES 50000
#define N_EDGES 500000
#define C_DIM 128

typedef __attribute__((ext_vector_type(8))) short bf8;
typedef __attribute__((ext_vector_type(4))) float f32x4;

__device__ __forceinline__ float bflo(unsigned u) { return __uint_as_float(u << 16); }
__device__ __forceinline__ float bfhi(unsigned u) { return __uint_as_float(u & 0xffff0000u); }
__device__ __forceinline__ unsigned short f2bfu(float f) {
    __hip_bfloat16 h = __float2bfloat16(f);
    unsigned short u;
    __builtin_memcpy(&u, &h, 2);
    return u;
}
__device__ __forceinline__ unsigned packbf(float a, float b) {
    return ((unsigned)f2bfu(b) << 16) | f2bfu(a);
}

// ---------------- graph preprocessing ----------------

__global__ void count_deg(const int* __restrict__ row, const int* __restrict__ col,
                          int* __restrict__ dout, int* __restrict__ din, int e) {
    int i = blockIdx.x * blockDim.x + threadIdx.x;
    if (i >= e) return;
    atomicAdd(&dout[row[i]], 1);
    atomicAdd(&din[col[i]], 1);
}

__global__ void scan_block(const int* __restrict__ counts, int* __restrict__ excl,
                           int* __restrict__ blocksums, int n) {
    __shared__ int tmp[1024];
    int tid = threadIdx.x;
    int gid = blockIdx.x * 1024 + tid;
    int v = (gid < n) ? counts[gid] : 0;
    tmp[tid] = v;
    __syncthreads();
    for (int off = 1; off < 1024; off <<= 1) {
        int t = (tid >= off) ? tmp[tid - off] : 0;
        __syncthreads();
        tmp[tid] += t;
        __syncthreads();
    }
    int incl = tmp[tid];
    if (gid < n) excl[gid] = incl - v;
    if (tid == 1023) blocksums[blockIdx.x] = incl;
}

__global__ void scan_sums(int* __restrict__ blocksums, int nb) {
    __shared__ int tmp[64];
    int tid = threadIdx.x;
    int v = (tid < nb) ? blocksums[tid] : 0;
    tmp[tid] = v;
    __syncthreads();
    for (int off = 1; off < 64; off <<= 1) {
        int t = (tid >= off) ? tmp[tid - off] : 0;
        __syncthreads();
        tmp[tid] += t;
        __syncthreads();
    }
    if (tid < nb) blocksums[tid] = tmp[tid] - v;
}

// rowptr finalize + cursor init + per-node inverse degrees (float2 {1/dout, 1/din})
__global__ void scan_add(int* __restrict__ rowptr, const int* __restrict__ blocksums,
                         int* __restrict__ cursor, const int* __restrict__ dout,
                         const int* __restrict__ din, float2* __restrict__ winv,
                         int n, int e_total) {
    int gid = blockIdx.x * blockDim.x + threadIdx.x;
    if (gid < n) {
        int v = rowptr[gid] + blocksums[gid >> 10];
        rowptr[gid] = v;
        cursor[gid] = v;
        winv[gid] = make_float2(1.0f / (float)dout[gid], 1.0f / (float)din[gid]);
    }
    if (gid == n) rowptr[n] = e_total;
}

__global__ void build_csr(const int* __restrict__ row, const int* __restrict__ col,
                          const float2* __restrict__ winv,
                          int* __restrict__ cursor, int* __restrict__ src,
                          float2* __restrict__ w, int e) {
    int i = blockIdx.x * blockDim.x + threadIdx.x;
    if (i >= e) return;
    int r = row[i], c = col[i];
    int pos = atomicAdd(&cursor[c], 1);
    src[pos] = r;
    w[pos] = winv[r];  // {1/deg_out[r], 1/deg_in[r]}
}

// ---------------- weight packing (bf16, [n][640] with interleaved-k order) ---
// raw W (2,3,128,64): idx(d,kk,k,j)
__device__ __forceinline__ float wraw(const float* W, int d, int kk, int k, int j) {
    return W[((d * 3 + kk) * 128 + k) * 64 + j];
}

// zr k-order: [0,128) XH rows; [128,384) P1 (pair p, sub: 0,1=o row 2p,2p+1; 2,3=i);
// [384,640) P2 same with kk=2.
// h  k-order: [0,64) XH X-rows; [64,192) P1 X-part; [192,320) P2 X-part;
// [320,384) HR rows (raw rows 64..127 of kk=0); [384,512) Q1; [512,640) Q2.
__global__ void pack_weights(const float* __restrict__ Wz, const float* __restrict__ Wr,
                             const float* __restrict__ Wh,
                             unsigned short* __restrict__ Wzr_t,   // [128][640]
                             unsigned short* __restrict__ Wh_t) {  // [64][640]
    int i = blockIdx.x * blockDim.x + threadIdx.x;
    if (i < 128 * 640) {
        int k = i % 640;
        int nn = i / 640;
        const float* W = (nn < 64) ? Wz : Wr;
        int j = nn & 63;
        float v;
        if (k < 128) {
            v = wraw(W, 0, 0, k, j) + wraw(W, 1, 0, k, j);
        } else {
            int k2 = k - 128;
            int kk = (k2 >= 256) ? 2 : 1;
            int k3 = k2 & 255;
            int p = k3 >> 2, sub = k3 & 3;
            v = wraw(W, sub >> 1, kk, 2 * p + (sub & 1), j);
        }
        Wzr_t[i] = f2bfu(v);
    } else if (i < 128 * 640 + 64 * 640) {
        int i2 = i - 128 * 640;
        int k = i2 % 640;
        int j = i2 / 640;
        float v;
        if (k < 64) {
            v = wraw(Wh, 0, 0, k, j) + wraw(Wh, 1, 0, k, j);
        } else if (k < 320) {
            int k2 = k - 64;
            int kk = (k2 >= 128) ? 2 : 1;
            int k3 = k2 & 127;
            int p = k3 >> 2, sub = k3 & 3;
            v = wraw(Wh, sub >> 1, kk, 2 * p + (sub & 1), j);
        } else if (k < 384) {
            int rr = k - 320;
            v = wraw(Wh, 0, 0, 64 + rr, j) + wraw(Wh, 1, 0, 64 + rr, j);
        } else {
            int k2 = k - 384;
            int kk = (k2 >= 128) ? 2 : 1;
            int k3 = k2 & 127;
            int p = k3 >> 2, sub = k3 & 3;
            v = wraw(Wh, sub >> 1, kk, 64 + 2 * p + (sub & 1), j);
        }
        Wh_t[i2] = f2bfu(v);
    }
}

// ---------------- concat ----------------

__global__ void concat_xh(const float* __restrict__ X, const float* __restrict__ H,
                          unsigned short* __restrict__ XH, int n) {
    int i = blockIdx.x * blockDim.x + threadIdx.x;
    if (i >= n * C_DIM) return;
    int r = i >> 7, c = i & 127;
    float v = (c < 64) ? X[r * 64 + c] : H[r * 64 + (c - 64)];
    XH[i] = f2bfu(v);
}

// ---------------- diffusion props ----------------
// P1/P2 layout: [n][256], lane handles pair p=lane: cols 4p..4p+3 = {o0,o1,i0,i1}
// Q1/Q2 layout: [n][128], 2 nodes/wave, p=lane&31: cols 4p..4p+3

__global__ void prop1_128(const unsigned short* __restrict__ S,
                          const int* __restrict__ rowptr, const int* __restrict__ src,
                          const float2* __restrict__ w,
                          unsigned short* __restrict__ P1, int n) {
    int node = (blockIdx.x * blockDim.x + threadIdx.x) >> 6;
    int lane = threadIdx.x & 63;
    if (node >= n) return;
    int beg = rowptr[node], end = rowptr[node + 1];
    float ao0 = 0.f, ao1 = 0.f, ai0 = 0.f, ai1 = 0.f;
    int j = beg;
    for (; j + 4 <= end; j += 4) {
        int s0 = src[j], s1 = src[j + 1], s2 = src[j + 2], s3 = src[j + 3];
        float2 w0 = w[j], w1 = w[j + 1], w2 = w[j + 2], w3 = w[j + 3];
        unsigned u0 = *(const unsigned*)(S + (size_t)s0 * 128 + 2 * lane);
        unsigned u1 = *(const unsigned*)(S + (size_t)s1 * 128 + 2 * lane);
        unsigned u2 = *(const unsigned*)(S + (size_t)s2 * 128 + 2 * lane);
        unsigned u3 = *(const unsigned*)(S + (size_t)s3 * 128 + 2 * lane);
        ao0 = fmaf(w0.x, bflo(u0), ao0); ao1 = fmaf(w0.x, bfhi(u0), ao1);
        ai0 = fmaf(w0.y, bflo(u0), ai0); ai1 = fmaf(w0.y, bfhi(u0), ai1);
        ao0 = fmaf(w1.x, bflo(u1), ao0); ao1 = fmaf(w1.x, bfhi(u1), ao1);
        ai0 = fmaf(w1.y, bflo(u1), ai0); ai1 = fmaf(w1.y, bfhi(u1), ai1);
        ao0 = fmaf(w2.x, bflo(u2), ao0); ao1 = fmaf(w2.x, bfhi(u2), ao1);
        ai0 = fmaf(w2.y, bflo(u2), ai0); ai1 = fmaf(w2.y, bfhi(u2), ai1);
        ao0 = fmaf(w3.x, bflo(u3), ao0); ao1 = fmaf(w3.x, bfhi(u3), ao1);
        ai0 = fmaf(w3.y, bflo(u3), ai0); ai1 = fmaf(w3.y, bfhi(u3), ai1);
    }
    for (; j < end; ++j) {
        int s = src[j];
        float2 wv = w[j];
        unsigned u = *(const unsigned*)(S + (size_t)s * 128 + 2 * lane);
        ao0 = fmaf(wv.x, bflo(u), ao0); ao1 = fmaf(wv.x, bfhi(u), ao1);
        ai0 = fmaf(wv.y, bflo(u), ai0); ai1 = fmaf(wv.y, bfhi(u), ai1);
    }
    uint2 out;
    out.x = packbf(ao0, ao1);
    out.y = packbf(ai0, ai1);
    *(uint2*)(P1 + (size_t)node * 256 + 4 * lane) = out;
}

__global__ void prop2_128(const unsigned short* __restrict__ P1,
                          const unsigned short* __restrict__ Xc,
                          const int* __restrict__ rowptr, const int* __restrict__ src,
                          const float2* __restrict__ w,
                          unsigned short* __restrict__ P2, int n) {
    int node = (blockIdx.x * blockDim.x + threadIdx.x) >> 6;
    int lane = threadIdx.x & 63;
    if (node >= n) return;
    int beg = rowptr[node], end = rowptr[node + 1];
    float ao0 = 0.f, ao1 = 0.f, ai0 = 0.f, ai1 = 0.f;
    int j = beg;
    for (; j + 4 <= end; j += 4) {
        int s0 = src[j], s1 = src[j + 1], s2 = src[j + 2], s3 = src[j + 3];
        float2 w0 = w[j], w1 = w[j + 1], w2 = w[j + 2], w3 = w[j + 3];
        uint2 v0 = *(const uint2*)(P1 + (size_t)s0 * 256 + 4 * lane);
        uint2 v1 = *(const uint2*)(P1 + (size_t)s1 * 256 + 4 * lane);
        uint2 v2 = *(const uint2*)(P1 + (size_t)s2 * 256 + 4 * lane);
        uint2 v3 = *(const uint2*)(P1 + (size_t)s3 * 256 + 4 * lane);
        ao0 = fmaf(w0.x, bflo(v0.x), ao0); ao1 = fmaf(w0.x, bfhi(v0.x), ao1);
        ai0 = fmaf(w0.y, bflo(v0.y), ai0); ai1 = fmaf(w0.y, bfhi(v0.y), ai1);
        ao0 = fmaf(w1.x, bflo(v1.x), ao0); ao1 = fmaf(w1.x, bfhi(v1.x), ao1);
        ai0 = fmaf(w1.y, bflo(v1.y), ai0); ai1 = fmaf(w1.y, bfhi(v1.y), ai1);
        ao0 = fmaf(w2.x, bflo(v2.x), ao0); ao1 = fmaf(w2.x, bfhi(v2.x), ao1);
        ai0 = fmaf(w2.y, bflo(v2.y), ai0); ai1 = fmaf(w2.y, bfhi(v2.y), ai1);
        ao0 = fmaf(w3.x, bflo(v3.x), ao0); ao1 = fmaf(w3.x, bfhi(v3.x), ao1);
        ai0 = fmaf(w3.y, bflo(v3.y), ai0); ai1 = fmaf(w3.y, bfhi(v3.y), ai1);
    }
    for (; j < end; ++j) {
        int s = src[j];
        float2 wv = w[j];
        uint2 v = *(const uint2*)(P1 + (size_t)s * 256 + 4 * lane);
        ao0 = fmaf(wv.x, bflo(v.x), ao0); ao1 = fmaf(wv.x, bfhi(v.x), ao1);
        ai0 = fmaf(wv.y, bflo(v.y), ai0); ai1 = fmaf(wv.y, bfhi(v.y), ai1);
    }
    unsigned ux = *(const unsigned*)(Xc + (size_t)node * 128 + 2 * lane);
    float x0 = bflo(ux), x1 = bfhi(ux);
    uint2 out;
    out.x = packbf(2.f * ao0 - x0, 2.f * ao1 - x1);
    out.y = packbf(2.f * ai0 - x0, 2.f * ai1 - x1);
    *(uint2*)(P2 + (size_t)node * 256 + 4 * lane) = out;
}

// 64-col props: 2 nodes per wave (half-wave each), divergence-tolerant per-lane loop
__global__ void prop1_64(const unsigned short* __restrict__ HR,
                         const int* __restrict__ rowptr, const int* __restrict__ src,
                         const float2* __restrict__ w,
                         unsigned short* __restrict__ Q1, int n) {
    int tid = blockIdx.x * blockDim.x + threadIdx.x;
    int lane = tid & 63;
    int node = (tid >> 6) * 2 + (lane >> 5);
    int p = lane & 31;
    if (node >= n) return;
    int beg = rowptr[node], end = rowptr[node + 1];
    float ao0 = 0.f, ao1 = 0.f, ai0 = 0.f, ai1 = 0.f;
    int j = beg;
    for (; j + 4 <= end; j += 4) {
        int s0 = src[j], s1 = src[j + 1], s2 = src[j + 2], s3 = src[j + 3];
        float2 w0 = w[j], w1 = w[j + 1], w2 = w[j + 2], w3 = w[j + 3];
        unsigned u0 = *(const unsigned*)(HR + (size_t)s0 * 64 + 2 * p);
        unsigned u1 = *(const unsigned*)(HR + (size_t)s1 * 64 + 2 * p);
        unsigned u2 = *(const unsigned*)(HR + (size_t)s2 * 64 + 2 * p);
        unsigned u3 = *(const unsigned*)(HR + (size_t)s3 * 64 + 2 * p);
        ao0 = fmaf(w0.x, bflo(u0), ao0); ao1 = fmaf(w0.x, bfhi(u0), ao1);
        ai0 = fmaf(w0.y, bflo(u0), ai0); ai1 = fmaf(w0.y, bfhi(u0), ai1);
        ao0 = fmaf(w1.x, bflo(u1), ao0); ao1 = fmaf(w1.x, bfhi(u1), ao1);
        ai0 = fmaf(w1.y, bflo(u1), ai0); ai1 = fmaf(w1.y, bfhi(u1), ai1);
        ao0 = fmaf(w2.x, bflo(u2), ao0); ao1 = fmaf(w2.x, bfhi(u2), ao1);
        ai0 = fmaf(w2.y, bflo(u2), ai0); ai1 = fmaf(w2.y, bfhi(u2), ai1);
        ao0 = fmaf(w3.x, bflo(u3), ao0); ao1 = fmaf(w3.x, bfhi(u3), ao1);
        ai0 = fmaf(w3.y, bflo(u3), ai0); ai1 = fmaf(w3.y, bfhi(u3), ai1);
    }
    for (; j < end; ++j) {
        int s = src[j];
        float2 wv = w[j];
        unsigned u = *(const unsigned*)(HR + (size_t)s * 64 + 2 * p);
        ao0 = fmaf(wv.x, bflo(u), ao0); ao1 = fmaf(wv.x, bfhi(u), ao1);
        ai0 = fmaf(wv.y, bflo(u), ai0); ai1 = fmaf(wv.y, bfhi(u), ai1);
    }
    uint2 out;
    out.x = packbf(ao0, ao1);
    out.y = packbf(ai0, ai1);
    *(uint2*)(Q1 + (size_t)node * 128 + 4 * p) = out;
}

__global__ void prop2_64(const unsigned short* __restrict__ Q1,
                         const unsigned short* __restrict__ HR,
                         const int* __restrict__ rowptr, const int* __restrict__ src,
                         const float2* __restrict__ w,
                         unsigned short* __restrict__ Q2, int n) {
    int tid = blockIdx.x * blockDim.x + threadIdx.x;
    int lane = tid & 63;
    int node = (tid >> 6) * 2 + (lane >> 5);
    int p = lane & 31;
    if (node >= n) return;
    int beg = rowptr[node], end = rowptr[node + 1];
    float ao0 = 0.f, ao1 = 0.f, ai0 = 0.f, ai1 = 0.f;
    int j = beg;
    for (; j + 4 <= end; j += 4) {
        int s0 = src[j], s1 = src[j + 1], s2 = src[j + 2], s3 = src[j + 3];
        float2 w0 = w[j], w1 = w[j + 1], w2 = w[j + 2], w3 = w[j + 3];
        uint2 v0 = *(const uint2*)(Q1 + (size_t)s0 * 128 + 4 * p);
        uint2 v1 = *(const uint2*)(Q1 + (size_t)s1 * 128 + 4 * p);
        uint2 v2 = *(const uint2*)(Q1 + (size_t)s2 * 128 + 4 * p);
        uint2 v3 = *(const uint2*)(Q1 + (size_t)s3 * 128 + 4 * p);
        ao0 = fmaf(w0.x, bflo(v0.x), ao0); ao1 = fmaf(w0.x, bfhi(v0.x), ao1);
        ai0 = fmaf(w0.y, bflo(v0.y), ai0); ai1 = fmaf(w0.y, bfhi(v0.y), ai1);
        ao0 = fmaf(w1.x, bflo(v1.x), ao0); ao1 = fmaf(w1.x, bfhi(v1.x), ao1);
        ai0 = fmaf(w1.y, bflo(v1.y), ai0); ai1 = fmaf(w1.y, bfhi(v1.y), ai1);
        ao0 = fmaf(w2.x, bflo(v2.x), ao0); ao1 = fmaf(w2.x, bfhi(v2.x), ao1);
        ai0 = fmaf(w2.y, bflo(v2.y), ai0); ai1 = fmaf(w2.y, bfhi(v2.y), ai1);
        ao0 = fmaf(w3.x, bflo(v3.x), ao0); ao1 = fmaf(w3.x, bfhi(v3.x), ao1);
        ai0 = fmaf(w3.y, bflo(v3.y), ai0); ai1 = fmaf(w3.y, bfhi(v3.y), ai1);
    }
    for (; j < end; ++j) {
        int s = src[j];
        float2 wv = w[j];
        uint2 v = *(const uint2*)(Q1 + (size_t)s * 128 + 4 * p);
        ao0 = fmaf(wv.x, bflo(v.x), ao0); ao1 = fmaf(wv.x, bfhi(v.x), ao1);
        ai0 = fmaf(wv.y, bflo(v.y), ai0); ai1 = fmaf(wv.y, bfhi(v.y), ai1);
    }
    unsigned ux = *(const unsigned*)(HR + (size_t)node * 64 + 2 * p);
    float x0 = bflo(ux), x1 = bfhi(ux);
    uint2 out;
    out.x = packbf(2.f * ao0 - x0, 2.f * ao1 - x1);
    out.y = packbf(2.f * ai0 - x0, 2.f * ai1 - x1);
    *(uint2*)(Q2 + (size_t)node * 128 + 4 * p) = out;
}

// ---------------- MFMA GEMMs ----------------
// mfma_f32_16x16x32_bf16: A[m=lane&15][k=quad*8+j]; B[k=quad*8+j][n=lane&15];
// C/D: col=lane&15, row=quad*4+reg.

// ZR: A segments {XH(128,s128), P1(256,s256), P2(256,s256)}, W=[128][640].
// Epilogue: Z -> Zf fp32, R -> HR = H*R bf16.
__global__ __launch_bounds__(256) void gemm_zr_mfma(
    const unsigned short* __restrict__ XH, const unsigned short* __restrict__ P1,
    const unsigned short* __restrict__ P2,
    const unsigned short* __restrict__ Wt, const float* __restrict__ bz,
    const float* __restrict__ br, const float* __restrict__ H,
    float* __restrict__ Zf, unsigned short* __restrict__ HR, int n) {
    int lane = threadIdx.x & 63;
    int wave = blockIdx.x * 4 + (threadIdx.x >> 6);
    int rowbase = wave * 32;
    if (rowbase >= n) return;
    int lr = lane & 15;
    int quad = lane >> 4;
    int r0 = rowbase + lr;       if (r0 >= n) r0 = n - 1;
    int r1 = rowbase + 16 + lr;  if (r1 >= n) r1 = n - 1;

    f32x4 zero = {0.f, 0.f, 0.f, 0.f};
    f32x4 acc[2][8];
#pragma unroll
    for (int a = 0; a < 2; ++a)
#pragma unroll
        for (int b = 0; b < 8; ++b) acc[a][b] = zero;

    const unsigned short* bases[3] = {XH, P1, P2};
    const int strides[3] = {128, 256, 256};
    const int nch[3] = {4, 8, 8};
    int kg = 0;
#pragma unroll
    for (int sg = 0; sg < 3; ++sg) {
        const unsigned short* A0 = bases[sg] + (size_t)r0 * strides[sg] + quad * 8;
        const unsigned short* A1 = bases[sg] + (size_t)r1 * strides[sg] + quad * 8;
#pragma unroll
        for (int kk = 0; kk < nch[sg]; ++kk) {
            bf8 a0 = *(const bf8*)(A0 + kk * 32);
            bf8 a1 = *(const bf8*)(A1 + kk * 32);
#pragma unroll
            for (int nt = 0; nt < 8; ++nt) {
                bf8 b = *(const bf8*)(Wt + (size_t)(nt * 16 + lr) * 640 + kg + kk * 32 + quad * 8);
                acc[0][nt] = __builtin_amdgcn_mfma_f32_16x16x32_bf16(a0, b, acc[0][nt], 0, 0, 0);
                acc[1][nt] = __builtin_amdgcn_mfma_f32_16x16x32_bf16(a1, b, acc[1][nt], 0, 0, 0);
            }
        }
        kg += nch[sg] * 32;
    }
#pragma unroll
    for (int mt = 0; mt < 2; ++mt)
#pragma unroll
        for (int reg = 0; reg < 4; ++reg) {
            int r = rowbase + mt * 16 + quad * 4 + reg;
            if (r >= n) continue;
#pragma unroll
            for (int nt = 0; nt < 8; ++nt) {
                int c = nt * 16 + lr;
                float bias = (c < 64) ? bz[c] : br[c - 64];
                float v = acc[mt][nt][reg] + bias;
                float s = 1.f / (1.f + expf(-v));
                if (nt < 4) {
                    Zf[(size_t)r * 64 + c] = s;
                } else {
                    int c2 = c - 64;
                    HR[(size_t)r * 64 + c2] = f2bfu(H[(size_t)r * 64 + c2] * s);
                }
            }
        }
}

// H~: A segments {XH(64,s128), P1(128,s256), P2(128,s256), HR(64,s64), Q1(128,s128), Q2(128,s128)}
__global__ __launch_bounds__(256) void gemm_h_mfma(
    const unsigned short* __restrict__ XH, const unsigned short* __restrict__ P1,
    const unsigned short* __restrict__ P2, const unsigned short* __restrict__ HR,
    const unsigned short* __restrict__ Q1, const unsigned short* __restrict__ Q2,
    const unsigned short* __restrict__ Wt, const float* __restrict__ bh,
    const float* __restrict__ Zf, const float* __restrict__ H,
    float* __restrict__ out, int n) {
    int lane = threadIdx.x & 63;
    int wave = blockIdx.x * 4 + (threadIdx.x >> 6);
    int rowbase = wave * 32;
    if (rowbase >= n) return;
    int lr = lane & 15;
    int quad = lane >> 4;
    int r0 = rowbase + lr;       if (r0 >= n) r0 = n - 1;
    int r1 = rowbase + 16 + lr;  if (r1 >= n) r1 = n - 1;

    f32x4 zero = {0.f, 0.f, 0.f, 0.f};
    f32x4 acc[2][4];
#pragma unroll
    for (int a = 0; a < 2; ++a)
#pragma unroll
        for (int b = 0; b < 4; ++b) acc[a][b] = zero;

    const unsigned short* bases[6] = {XH, P1, P2, HR, Q1, Q2};
    const int strides[6] = {128, 256, 256, 64, 128, 128};
    const int nch[6] = {2, 4, 4, 2, 4, 4};
    int kg = 0;
#pragma unroll
    for (int sg = 0; sg < 6; ++sg) {
        const unsigned short* A0 = bases[sg] + (size_t)r0 * strides[sg] + quad * 8;
        const unsigned short* A1 = bases[sg] + (size_t)r1 * strides[sg] + quad * 8;
#pragma unroll
        for (int kk = 0; kk < nch[sg]; ++kk) {
            bf8 a0 = *(const bf8*)(A0 + kk * 32);
            bf8 a1 = *(const bf8*)(A1 + kk * 32);
#pragma unroll
            for (int nt = 0; nt < 4; ++nt) {
                bf8 b = *(const bf8*)(Wt + (size_t)(nt * 16 + lr) * 640 + kg + kk * 32 + quad * 8);
                acc[0][nt] = __builtin_amdgcn_mfma_f32_16x16x32_bf16(a0, b, acc[0][nt], 0, 0, 0);
                acc[1][nt] = __builtin_amdgcn_mfma_f32_16x16x32_bf16(a1, b, acc[1][nt], 0, 0, 0);
            }
        }
        kg += nch[sg] * 32;
    }
#pragma unroll
    for (int mt = 0; mt < 2; ++mt)
#pragma unroll
        for (int reg = 0; reg < 4; ++reg) {
            int r = rowbase + mt * 16 + quad * 4 + reg;
            if (r >= n) continue;
#pragma unroll
            for (int nt = 0; nt < 4; ++nt) {
                int c = nt * 16 + lr;
                float ht = tanhf(acc[mt][nt][reg] + bh[c]);
                float z = Zf[(size_t)r * 64 + c];
                float h_old = H[(size_t)r * 64 + c];
                out[(size_t)r * 64 + c] = z * h_old + (1.f - z) * ht;
            }
        }
}

// ---------------- launch ----------------

static inline size_t rup(size_t x) { return (x + 63) & ~(size_t)63; }

extern "C" void kernel_launch(void* const* d_in, const int* in_sizes, int n_in,
                              void* d_out, int out_size, void* d_ws, size_t ws_size,
                              hipStream_t stream) {
    const float* X  = (const float*)d_in[0];
    const int*   EI = (const int*)d_in[1];
    const float* H  = (const float*)d_in[2];
    const float* Wz = (const float*)d_in[3];
    const float* bz = (const float*)d_in[4];
    const float* Wr = (const float*)d_in[5];
    const float* br = (const float*)d_in[6];
    const float* Wh = (const float*)d_in[7];
    const float* bh = (const float*)d_in[8];
    float* out = (float*)d_out;

    const int* row = EI;
    const int* col = EI + N_EDGES;

    char* ws = (char*)d_ws;
    size_t off = 0;
    auto carve = [&](size_t bytes) { void* p = ws + off; off += rup(bytes); return p; };

    int*   deg_out   = (int*)carve(N_NODES * 4);
    int*   deg_in    = (int*)carve(N_NODES * 4);
    int*   rowptr    = (int*)carve((N_NODES + 1) * 4);
    int*   cursor    = (int*)carve(N_NODES * 4);
    int*   blocksums = (int*)carve(64 * 4);
    float2* winv     = (float2*)carve(N_NODES * 8);
    int*   csr_src   = (int*)carve(N_EDGES * 4);
    float2* csr_w    = (float2*)carve(N_EDGES * 8);
    unsigned short* XH = (unsigned short*)carve((size_t)N_NODES * 128 * 2);
    unsigned short* P1 = (unsigned short*)carve((size_t)N_NODES * 256 * 2);
    unsigned short* P2 = (unsigned short*)carve((size_t)N_NODES * 256 * 2);
    unsigned short* HR = (unsigned short*)carve((size_t)N_NODES * 64 * 2);
    unsigned short* Q1 = (unsigned short*)carve((size_t)N_NODES * 128 * 2);
    unsigned short* Q2 = (unsigned short*)carve((size_t)N_NODES * 128 * 2);
    float* Zf          = (float*)carve((size_t)N_NODES * 64 * 4);
    unsigned short* Wzr_t = (unsigned short*)carve(128 * 640 * 2);
    unsigned short* Wh_t  = (unsigned short*)carve(64 * 640 * 2);

    // degrees
    hipMemsetAsync(deg_out, 0, rup(N_NODES * 4) + rup(N_NODES * 4), stream);
    count_deg<<<(N_EDGES + 255) / 256, 256, 0, stream>>>(row, col, deg_out, deg_in, N_EDGES);

    // exclusive scan deg_in -> rowptr; winv
    int nblk = (N_NODES + 1023) / 1024;
    scan_block<<<nblk, 1024, 0, stream>>>(deg_in, rowptr, blocksums, N_NODES);
    scan_sums<<<1, 64, 0, stream>>>(blocksums, nblk);
    scan_add<<<(N_NODES + 1 + 255) / 256, 256, 0, stream>>>(rowptr, blocksums, cursor,
                                                            deg_out, deg_in, winv, N_NODES, N_EDGES);

    // CSR by destination
    build_csr<<<(N_EDGES + 255) / 256, 256, 0, stream>>>(row, col, winv, cursor,
                                                         csr_src, csr_w, N_EDGES);

    // weights (both packs in one kernel)
    pack_weights<<<(128 * 640 + 64 * 640 + 255) / 256, 256, 0, stream>>>(Wz, Wr, Wh, Wzr_t, Wh_t);

    // XH = [X, H] bf16
    concat_xh<<<(N_NODES * C_DIM + 255) / 256, 256, 0, stream>>>(X, H, XH, N_NODES);

    // props on XH
    int blocks128 = (N_NODES * 64 + 255) / 256;       // one wave per node
    prop1_128<<<blocks128, 256, 0, stream>>>(XH, rowptr, csr_src, csr_w, P1, N_NODES);
    prop2_128<<<blocks128, 256, 0, stream>>>(P1, XH, rowptr, csr_src, csr_w, P2, N_NODES);

    // Z|R GEMM -> Zf, HR (= H*R)
    int gemm_blocks = (N_NODES + 127) / 128;
    gemm_zr_mfma<<<gemm_blocks, 256, 0, stream>>>(XH, P1, P2, Wzr_t, bz, br, H, Zf, HR, N_NODES);

    // props on HR (2 nodes per wave)
    int blocks64 = ((N_NODES + 1) / 2 * 64 + 255) / 256;
    prop1_64<<<blocks64, 256, 0, stream>>>(HR, rowptr, csr_src, csr_w, Q1, N_NODES);
    prop2_64<<<blocks64, 256, 0, stream>>>(Q1, HR, rowptr, csr_src, csr_w, Q2, N_NODES);

    // H~ GEMM + GRU mix -> out
    gemm_h_mfma<<<gemm_blocks, 256, 0, stream>>>(XH, P1, P2, HR, Q1, Q2,
                                                 Wh_t, bh, Zf, H, out, N_NODES);
}

// Round 4
// 393.020 us; speedup vs baseline: 2.2867x; 1.0189x over previous
//
#include <hip/hip_runtime.h>
#include <hip/hip_bf16.h>
#include <math.h>

#define N_NODES 50000
#define N_EDGES 500000
#define C_DIM 128

typedef __attribute__((ext_vector_type(8))) short bf8;
typedef __attribute__((ext_vector_type(4))) float f32x4;

__device__ __forceinline__ float bflo(unsigned u) { return __uint_as_float(u << 16); }
__device__ __forceinline__ float bfhi(unsigned u) { return __uint_as_float(u & 0xffff0000u); }
__device__ __forceinline__ unsigned short f2bfu(float f) {
    __hip_bfloat16 h = __float2bfloat16(f);
    unsigned short u;
    __builtin_memcpy(&u, &h, 2);
    return u;
}
__device__ __forceinline__ unsigned packbf(float a, float b) {
    return ((unsigned)f2bfu(b) << 16) | f2bfu(a);
}

// ---------------- graph preprocessing ----------------

__global__ void count_deg(const int* __restrict__ row, const int* __restrict__ col,
                          int* __restrict__ dout, int* __restrict__ din, int e) {
    int i = blockIdx.x * blockDim.x + threadIdx.x;
    if (i >= e) return;
    atomicAdd(&dout[row[i]], 1);
    atomicAdd(&din[col[i]], 1);
}

__global__ void scan_block(const int* __restrict__ counts, int* __restrict__ excl,
                           int* __restrict__ blocksums, int n) {
    __shared__ int tmp[1024];
    int tid = threadIdx.x;
    int gid = blockIdx.x * 1024 + tid;
    int v = (gid < n) ? counts[gid] : 0;
    tmp[tid] = v;
    __syncthreads();
    for (int off = 1; off < 1024; off <<= 1) {
        int t = (tid >= off) ? tmp[tid - off] : 0;
        __syncthreads();
        tmp[tid] += t;
        __syncthreads();
    }
    int incl = tmp[tid];
    if (gid < n) excl[gid] = incl - v;
    if (tid == 1023) blocksums[blockIdx.x] = incl;
}

__global__ void scan_sums(int* __restrict__ blocksums, int nb) {
    __shared__ int tmp[64];
    int tid = threadIdx.x;
    int v = (tid < nb) ? blocksums[tid] : 0;
    tmp[tid] = v;
    __syncthreads();
    for (int off = 1; off < 64; off <<= 1) {
        int t = (tid >= off) ? tmp[tid - off] : 0;
        __syncthreads();
        tmp[tid] += t;
        __syncthreads();
    }
    if (tid < nb) blocksums[tid] = tmp[tid] - v;
}

__global__ void scan_add(int* __restrict__ rowptr, const int* __restrict__ blocksums,
                         int* __restrict__ cursor, const int* __restrict__ dout,
                         const int* __restrict__ din, float2* __restrict__ winv,
                         int n, int e_total) {
    int gid = blockIdx.x * blockDim.x + threadIdx.x;
    if (gid < n) {
        int v = rowptr[gid] + blocksums[gid >> 10];
        rowptr[gid] = v;
        cursor[gid] = v;
        winv[gid] = make_float2(1.0f / (float)dout[gid], 1.0f / (float)din[gid]);
    }
    if (gid == n) rowptr[n] = e_total;
}

__global__ void build_csr(const int* __restrict__ row, const int* __restrict__ col,
                          const float2* __restrict__ winv,
                          int* __restrict__ cursor, int* __restrict__ src,
                          float2* __restrict__ w, int e) {
    int i = blockIdx.x * blockDim.x + threadIdx.x;
    if (i >= e) return;
    int r = row[i], c = col[i];
    int pos = atomicAdd(&cursor[c], 1);
    src[pos] = r;
    w[pos] = winv[r];
}

// ---------------- weight packing (bf16, [n][640], interleaved k-order) ------
__device__ __forceinline__ float wraw(const float* W, int d, int kk, int k, int j) {
    return W[((d * 3 + kk) * 128 + k) * 64 + j];
}

__global__ void pack_weights(const float* __restrict__ Wz, const float* __restrict__ Wr,
                             const float* __restrict__ Wh,
                             unsigned short* __restrict__ Wzr_t,   // [128][640]
                             unsigned short* __restrict__ Wh_t) {  // [64][640]
    int i = blockIdx.x * blockDim.x + threadIdx.x;
    if (i < 128 * 640) {
        int k = i % 640;
        int nn = i / 640;
        const float* W = (nn < 64) ? Wz : Wr;
        int j = nn & 63;
        float v;
        if (k < 128) {
            v = wraw(W, 0, 0, k, j) + wraw(W, 1, 0, k, j);
        } else {
            int k2 = k - 128;
            int kk = (k2 >= 256) ? 2 : 1;
            int k3 = k2 & 255;
            int p = k3 >> 2, sub = k3 & 3;
            v = wraw(W, sub >> 1, kk, 2 * p + (sub & 1), j);
        }
        Wzr_t[i] = f2bfu(v);
    } else if (i < 128 * 640 + 64 * 640) {
        int i2 = i - 128 * 640;
        int k = i2 % 640;
        int j = i2 / 640;
        float v;
        if (k < 64) {
            v = wraw(Wh, 0, 0, k, j) + wraw(Wh, 1, 0, k, j);
        } else if (k < 320) {
            int k2 = k - 64;
            int kk = (k2 >= 128) ? 2 : 1;
            int k3 = k2 & 127;
            int p = k3 >> 2, sub = k3 & 3;
            v = wraw(Wh, sub >> 1, kk, 2 * p + (sub & 1), j);
        } else if (k < 384) {
            int rr = k - 320;
            v = wraw(Wh, 0, 0, 64 + rr, j) + wraw(Wh, 1, 0, 64 + rr, j);
        } else {
            int k2 = k - 384;
            int kk = (k2 >= 128) ? 2 : 1;
            int k3 = k2 & 127;
            int p = k3 >> 2, sub = k3 & 3;
            v = wraw(Wh, sub >> 1, kk, 64 + 2 * p + (sub & 1), j);
        }
        Wh_t[i2] = f2bfu(v);
    }
}

// ---------------- concat ----------------

__global__ void concat_xh(const float* __restrict__ X, const float* __restrict__ H,
                          unsigned short* __restrict__ XH, int n) {
    int i = blockIdx.x * blockDim.x + threadIdx.x;
    if (i >= n * C_DIM) return;
    int r = i >> 7, c = i & 127;
    float v = (c < 64) ? X[r * 64 + c] : H[r * 64 + (c - 64)];
    XH[i] = f2bfu(v);
}

// ---------------- diffusion props ----------------
// P layout [n][256]: pair p (0..63): cols 4p..4p+3 = {o(2p), o(2p+1), i(2p), i(2p+1)}
// Q layout [n][128]: same with 32 pairs.

// 2 nodes/wave, 32 lanes each; lane p handles S cols 4p..4p+3 (uint2 load)
__global__ void prop1_128(const unsigned short* __restrict__ S,
                          const int* __restrict__ rowptr, const int* __restrict__ src,
                          const float2* __restrict__ w,
                          unsigned short* __restrict__ P1, int n) {
    int tid = blockIdx.x * blockDim.x + threadIdx.x;
    int lane = tid & 63;
    int node = ((tid >> 6) << 1) + (lane >> 5);
    int p = lane & 31;
    if (node >= n) return;
    int beg = rowptr[node], end = rowptr[node + 1];
    float ao0 = 0.f, ao1 = 0.f, ao2 = 0.f, ao3 = 0.f;
    float ai0 = 0.f, ai1 = 0.f, ai2 = 0.f, ai3 = 0.f;
    int j = beg;
#define P1STEP(s_, w_) {                                                     \
        uint2 u = *(const uint2*)(S + (size_t)(s_) * 128 + 4 * p);           \
        float c0 = bflo(u.x), c1 = bfhi(u.x), c2 = bflo(u.y), c3 = bfhi(u.y);\
        ao0 = fmaf(w_.x, c0, ao0); ao1 = fmaf(w_.x, c1, ao1);                \
        ao2 = fmaf(w_.x, c2, ao2); ao3 = fmaf(w_.x, c3, ao3);                \
        ai0 = fmaf(w_.y, c0, ai0); ai1 = fmaf(w_.y, c1, ai1);                \
        ai2 = fmaf(w_.y, c2, ai2); ai3 = fmaf(w_.y, c3, ai3); }
    for (; j + 4 <= end; j += 4) {
        int s0 = src[j], s1 = src[j + 1], s2 = src[j + 2], s3 = src[j + 3];
        float2 w0 = w[j], w1 = w[j + 1], w2 = w[j + 2], w3 = w[j + 3];
        P1STEP(s0, w0); P1STEP(s1, w1); P1STEP(s2, w2); P1STEP(s3, w3);
    }
    for (; j < end; ++j) {
        int s = src[j]; float2 wv = w[j];
        P1STEP(s, wv);
    }
#undef P1STEP
    uint4 o;
    o.x = packbf(ao0, ao1); o.y = packbf(ai0, ai1);
    o.z = packbf(ao2, ao3); o.w = packbf(ai2, ai3);
    *(uint4*)(P1 + (size_t)node * 256 + 8 * p) = o;
}

// 2 nodes/wave; lane p handles P1 cols 8p..8p+7 (uint4 load)
__global__ void prop2_128(const unsigned short* __restrict__ P1,
                          const unsigned short* __restrict__ Xc,
                          const int* __restrict__ rowptr, const int* __restrict__ src,
                          const float2* __restrict__ w,
                          unsigned short* __restrict__ P2, int n) {
    int tid = blockIdx.x * blockDim.x + threadIdx.x;
    int lane = tid & 63;
    int node = ((tid >> 6) << 1) + (lane >> 5);
    int p = lane & 31;
    if (node >= n) return;
    int beg = rowptr[node], end = rowptr[node + 1];
    float oa = 0.f, ob = 0.f, oc = 0.f, od = 0.f;
    float ia = 0.f, ib = 0.f, ic = 0.f, id = 0.f;
    int j = beg;
#define P2STEP(s_, w_) {                                                     \
        uint4 v = *(const uint4*)(P1 + (size_t)(s_) * 256 + 8 * p);          \
        oa = fmaf(w_.x, bflo(v.x), oa); ob = fmaf(w_.x, bfhi(v.x), ob);      \
        ia = fmaf(w_.y, bflo(v.y), ia); ib = fmaf(w_.y, bfhi(v.y), ib);      \
        oc = fmaf(w_.x, bflo(v.z), oc); od = fmaf(w_.x, bfhi(v.z), od);      \
        ic = fmaf(w_.y, bflo(v.w), ic); id = fmaf(w_.y, bfhi(v.w), id); }
    for (; j + 4 <= end; j += 4) {
        int s0 = src[j], s1 = src[j + 1], s2 = src[j + 2], s3 = src[j + 3];
        float2 w0 = w[j], w1 = w[j + 1], w2 = w[j + 2], w3 = w[j + 3];
        P2STEP(s0, w0); P2STEP(s1, w1); P2STEP(s2, w2); P2STEP(s3, w3);
    }
    for (; j < end; ++j) {
        int s = src[j]; float2 wv = w[j];
        P2STEP(s, wv);
    }
#undef P2STEP
    uint2 ux = *(const uint2*)(Xc + (size_t)node * 128 + 4 * p);
    float xa = bflo(ux.x), xb = bfhi(ux.x), xc = bflo(ux.y), xd = bfhi(ux.y);
    uint4 o;
    o.x = packbf(2.f * oa - xa, 2.f * ob - xb);
    o.y = packbf(2.f * ia - xa, 2.f * ib - xb);
    o.z = packbf(2.f * oc - xc, 2.f * od - xd);
    o.w = packbf(2.f * ic - xc, 2.f * id - xd);
    *(uint4*)(P2 + (size_t)node * 256 + 8 * p) = o;
}

// 4 nodes/wave, 16 lanes each; lane p handles HR cols 4p..4p+3
__global__ void prop1_64(const unsigned short* __restrict__ HR,
                         const int* __restrict__ rowptr, const int* __restrict__ src,
                         const float2* __restrict__ w,
                         unsigned short* __restrict__ Q1, int n) {
    int tid = blockIdx.x * blockDim.x + threadIdx.x;
    int lane = tid & 63;
    int node = ((tid >> 6) << 2) + (lane >> 4);
    int p = lane & 15;
    if (node >= n) return;
    int beg = rowptr[node], end = rowptr[node + 1];
    float ao0 = 0.f, ao1 = 0.f, ao2 = 0.f, ao3 = 0.f;
    float ai0 = 0.f, ai1 = 0.f, ai2 = 0.f, ai3 = 0.f;
    int j = beg;
#define Q1STEP(s_, w_) {                                                     \
        uint2 u = *(const uint2*)(HR + (size_t)(s_) * 64 + 4 * p);           \
        float c0 = bflo(u.x), c1 = bfhi(u.x), c2 = bflo(u.y), c3 = bfhi(u.y);\
        ao0 = fmaf(w_.x, c0, ao0); ao1 = fmaf(w_.x, c1, ao1);                \
        ao2 = fmaf(w_.x, c2, ao2); ao3 = fmaf(w_.x, c3, ao3);                \
        ai0 = fmaf(w_.y, c0, ai0); ai1 = fmaf(w_.y, c1, ai1);                \
        ai2 = fmaf(w_.y, c2, ai2); ai3 = fmaf(w_.y, c3, ai3); }
    for (; j + 4 <= end; j += 4) {
        int s0 = src[j], s1 = src[j + 1], s2 = src[j + 2], s3 = src[j + 3];
        float2 w0 = w[j], w1 = w[j + 1], w2 = w[j + 2], w3 = w[j + 3];
        Q1STEP(s0, w0); Q1STEP(s1, w1); Q1STEP(s2, w2); Q1STEP(s3, w3);
    }
    for (; j < end; ++j) {
        int s = src[j]; float2 wv = w[j];
        Q1STEP(s, wv);
    }
#undef Q1STEP
    uint4 o;
    o.x = packbf(ao0, ao1); o.y = packbf(ai0, ai1);
    o.z = packbf(ao2, ao3); o.w = packbf(ai2, ai3);
    *(uint4*)(Q1 + (size_t)node * 128 + 8 * p) = o;
}

__global__ void prop2_64(const unsigned short* __restrict__ Q1,
                         const unsigned short* __restrict__ HR,
                         const int* __restrict__ rowptr, const int* __restrict__ src,
                         const float2* __restrict__ w,
                         unsigned short* __restrict__ Q2, int n) {
    int tid = blockIdx.x * blockDim.x + threadIdx.x;
    int lane = tid & 63;
    int node = ((tid >> 6) << 2) + (lane >> 4);
    int p = lane & 15;
    if (node >= n) return;
    int beg = rowptr[node], end = rowptr[node + 1];
    float oa = 0.f, ob = 0.f, oc = 0.f, od = 0.f;
    float ia = 0.f, ib = 0.f, ic = 0.f, id = 0.f;
    int j = beg;
#define Q2STEP(s_, w_) {                                                     \
        uint4 v = *(const uint4*)(Q1 + (size_t)(s_) * 128 + 8 * p);          \
        oa = fmaf(w_.x, bflo(v.x), oa); ob = fmaf(w_.x, bfhi(v.x), ob);      \
        ia = fmaf(w_.y, bflo(v.y), ia); ib = fmaf(w_.y, bfhi(v.y), ib);      \
        oc = fmaf(w_.x, bflo(v.z), oc); od = fmaf(w_.x, bfhi(v.z), od);      \
        ic = fmaf(w_.y, bflo(v.w), ic); id = fmaf(w_.y, bfhi(v.w), id); }
    for (; j + 4 <= end; j += 4) {
        int s0 = src[j], s1 = src[j + 1], s2 = src[j + 2], s3 = src[j + 3];
        float2 w0 = w[j], w1 = w[j + 1], w2 = w[j + 2], w3 = w[j + 3];
        Q2STEP(s0, w0); Q2STEP(s1, w1); Q2STEP(s2, w2); Q2STEP(s3, w3);
    }
    for (; j < end; ++j) {
        int s = src[j]; float2 wv = w[j];
        Q2STEP(s, wv);
    }
#undef Q2STEP
    uint2 ux = *(const uint2*)(HR + (size_t)node * 64 + 4 * p);
    float xa = bflo(ux.x), xb = bfhi(ux.x), xc = bflo(ux.y), xd = bfhi(ux.y);
    uint4 o;
    o.x = packbf(2.f * oa - xa, 2.f * ob - xb);
    o.y = packbf(2.f * ia - xa, 2.f * ib - xb);
    o.z = packbf(2.f * oc - xc, 2.f * od - xd);
    o.w = packbf(2.f * ic - xc, 2.f * id - xd);
    *(uint4*)(Q2 + (size_t)node * 128 + 8 * p) = o;
}

// ---------------- MFMA GEMMs (LDS-staged W) ----------------
// mfma_f32_16x16x32_bf16: A[m=lane&15][k=quad*8+j]; B[k=quad*8+j][n=lane&15];
// C/D: col=lane&15, row=quad*4+reg.
// LDS W tile: row stride 66 uint2 (=132 bf16, +4 pad) to spread banks.

// ZR: block = 64 rows x 128 cols, 4 waves: wave (mhalf, nhalf) = 32 rows x 64 cols.
// K = 5 chunks of 128: {XH, P1.lo, P1.hi, P2.lo, P2.hi}
__global__ __launch_bounds__(256) void gemm_zr_mfma(
    const unsigned short* __restrict__ XH, const unsigned short* __restrict__ P1,
    const unsigned short* __restrict__ P2,
    const unsigned short* __restrict__ Wt, const float* __restrict__ bz,
    const float* __restrict__ br, const float* __restrict__ H,
    float* __restrict__ Zf, unsigned short* __restrict__ HR, int n) {
    __shared__ uint2 Wl[128 * 66];  // 128 rows x 132 bf16 = 33792 B
    int tid = threadIdx.x;
    int lane = tid & 63;
    int wid = tid >> 6;
    int mhalf = wid & 1, nhalf = wid >> 1;
    int rowbase = blockIdx.x * 64 + mhalf * 32;
    int lr = lane & 15, quad = lane >> 4;
    int r0 = rowbase + lr;       if (r0 >= n) r0 = n - 1;
    int r1 = rowbase + 16 + lr;  if (r1 >= n) r1 = n - 1;

    f32x4 zero = {0.f, 0.f, 0.f, 0.f};
    f32x4 acc[2][4];
#pragma unroll
    for (int a = 0; a < 2; ++a)
#pragma unroll
        for (int b = 0; b < 4; ++b) acc[a][b] = zero;

    const unsigned short* Ab[5] = {XH, P1, P1, P2, P2};
    const int Astr[5] = {128, 256, 256, 256, 256};
    const int Aoff[5] = {0, 0, 128, 0, 128};

    for (int c = 0; c < 5; ++c) {
        // stage W chunk [128 n][128 k] -> LDS
        const unsigned short* Wsrc = Wt + c * 128;
        for (int i = tid; i < 128 * 16; i += 256) {
            int nrow = i >> 4, kp = i & 15;
            uint4 v = *(const uint4*)(Wsrc + (size_t)nrow * 640 + kp * 8);
            *(uint4*)&Wl[nrow * 66 + kp * 2] = v;
        }
        __syncthreads();
        const unsigned short* A0 = Ab[c] + (size_t)r0 * Astr[c] + Aoff[c] + quad * 8;
        const unsigned short* A1 = Ab[c] + (size_t)r1 * Astr[c] + Aoff[c] + quad * 8;
#pragma unroll
        for (int kk = 0; kk < 4; ++kk) {
            bf8 a0 = *(const bf8*)(A0 + kk * 32);
            bf8 a1 = *(const bf8*)(A1 + kk * 32);
#pragma unroll
            for (int nt = 0; nt < 4; ++nt) {
                int nrow = nhalf * 64 + nt * 16 + lr;
                int base = nrow * 66 + kk * 8 + quad * 2;
                union { bf8 v; uint2 h[2]; } bb;
                bb.h[0] = Wl[base];
                bb.h[1] = Wl[base + 1];
                acc[0][nt] = __builtin_amdgcn_mfma_f32_16x16x32_bf16(a0, bb.v, acc[0][nt], 0, 0, 0);
                acc[1][nt] = __builtin_amdgcn_mfma_f32_16x16x32_bf16(a1, bb.v, acc[1][nt], 0, 0, 0);
            }
        }
        __syncthreads();
    }
#pragma unroll
    for (int mt = 0; mt < 2; ++mt)
#pragma unroll
        for (int reg = 0; reg < 4; ++reg) {
            int r = rowbase + mt * 16 + quad * 4 + reg;
            if (r >= n) continue;
#pragma unroll
            for (int nt = 0; nt < 4; ++nt) {
                int cidx = nhalf * 64 + nt * 16 + lr;
                float bias = (cidx < 64) ? bz[cidx] : br[cidx - 64];
                float v = acc[mt][nt][reg] + bias;
                float s = 1.f / (1.f + expf(-v));
                if (cidx < 64) {
                    Zf[(size_t)r * 64 + cidx] = s;
                } else {
                    int c2 = cidx - 64;
                    HR[(size_t)r * 64 + c2] = f2bfu(H[(size_t)r * 64 + c2] * s);
                }
            }
        }
}

// H~: block = 64 rows x 64 cols, 4 waves: wave = 32 rows x 32 cols.
// K segments: {XH:64, P1.X:128, P2.X:128, HR:64, Q1:128, Q2:128}
__global__ __launch_bounds__(256) void gemm_h_mfma(
    const unsigned short* __restrict__ XH, const unsigned short* __restrict__ P1,
    const unsigned short* __restrict__ P2, const unsigned short* __restrict__ HR,
    const unsigned short* __restrict__ Q1, const unsigned short* __restrict__ Q2,
    const unsigned short* __restrict__ Wt, const float* __restrict__ bh,
    const float* __restrict__ Zf, const float* __restrict__ H,
    float* __restrict__ out, int n) {
    __shared__ uint2 Wl[64 * 66];  // 64 rows x 132 bf16 = 16896 B
    int tid = threadIdx.x;
    int lane = tid & 63;
    int wid = tid >> 6;
    int mhalf = wid & 1, nhalf = wid >> 1;
    int rowbase = blockIdx.x * 64 + mhalf * 32;
    int lr = lane & 15, quad = lane >> 4;
    int r0 = rowbase + lr;       if (r0 >= n) r0 = n - 1;
    int r1 = rowbase + 16 + lr;  if (r1 >= n) r1 = n - 1;

    f32x4 zero = {0.f, 0.f, 0.f, 0.f};
    f32x4 acc[2][2];
#pragma unroll
    for (int a = 0; a < 2; ++a)
#pragma unroll
        for (int b = 0; b < 2; ++b) acc[a][b] = zero;

    const unsigned short* Ab[6] = {XH, P1, P2, HR, Q1, Q2};
    const int Astr[6] = {128, 256, 256, 64, 128, 128};
    const int Aklen[6] = {64, 128, 128, 64, 128, 128};
    const int Akg[6] = {0, 64, 192, 320, 384, 512};

    for (int sg = 0; sg < 6; ++sg) {
        int klen = Aklen[sg];
        int units = 64 * (klen >> 3);
        const unsigned short* Wsrc = Wt + Akg[sg];
        for (int i = tid; i < units; i += 256) {
            int kcnt = klen >> 3;
            int nrow = i / kcnt, kp = i % kcnt;
            uint4 v = *(const uint4*)(Wsrc + (size_t)nrow * 640 + kp * 8);
            *(uint4*)&Wl[nrow * 66 + kp * 2] = v;
        }
        __syncthreads();
        const unsigned short* A0 = Ab[sg] + (size_t)r0 * Astr[sg] + quad * 8;
        const unsigned short* A1 = Ab[sg] + (size_t)r1 * Astr[sg] + quad * 8;
        int nkk = klen >> 5;
        for (int kk = 0; kk < nkk; ++kk) {
            bf8 a0 = *(const bf8*)(A0 + kk * 32);
            bf8 a1 = *(const bf8*)(A1 + kk * 32);
#pragma unroll
            for (int nt = 0; nt < 2; ++nt) {
                int nrow = nhalf * 32 + nt * 16 + lr;
                int base = nrow * 66 + kk * 8 + quad * 2;
                union { bf8 v; uint2 h[2]; } bb;
                bb.h[0] = Wl[base];
                bb.h[1] = Wl[base + 1];
                acc[0][nt] = __builtin_amdgcn_mfma_f32_16x16x32_bf16(a0, bb.v, acc[0][nt], 0, 0, 0);
                acc[1][nt] = __builtin_amdgcn_mfma_f32_16x16x32_bf16(a1, bb.v, acc[1][nt], 0, 0, 0);
            }
        }
        __syncthreads();
    }
#pragma unroll
    for (int mt = 0; mt < 2; ++mt)
#pragma unroll
        for (int reg = 0; reg < 4; ++reg) {
            int r = rowbase + mt * 16 + quad * 4 + reg;
            if (r >= n) continue;
#pragma unroll
            for (int nt = 0; nt < 2; ++nt) {
                int cidx = nhalf * 32 + nt * 16 + lr;
                float ht = tanhf(acc[mt][nt][reg] + bh[cidx]);
                float z = Zf[(size_t)r * 64 + cidx];
                float h_old = H[(size_t)r * 64 + cidx];
                out[(size_t)r * 64 + cidx] = z * h_old + (1.f - z) * ht;
            }
        }
}

// ---------------- launch ----------------

static inline size_t rup(size_t x) { return (x + 63) & ~(size_t)63; }

extern "C" void kernel_launch(void* const* d_in, const int* in_sizes, int n_in,
                              void* d_out, int out_size, void* d_ws, size_t ws_size,
                              hipStream_t stream) {
    const float* X  = (const float*)d_in[0];
    const int*   EI = (const int*)d_in[1];
    const float* H  = (const float*)d_in[2];
    const float* Wz = (const float*)d_in[3];
    const float* bz = (const float*)d_in[4];
    const float* Wr = (const float*)d_in[5];
    const float* br = (const float*)d_in[6];
    const float* Wh = (const float*)d_in[7];
    const float* bh = (const float*)d_in[8];
    float* out = (float*)d_out;

    const int* row = EI;
    const int* col = EI + N_EDGES;

    char* ws = (char*)d_ws;
    size_t off = 0;
    auto carve = [&](size_t bytes) { void* p = ws + off; off += rup(bytes); return p; };

    int*   deg_out   = (int*)carve(N_NODES * 4);
    int*   deg_in    = (int*)carve(N_NODES * 4);
    int*   rowptr    = (int*)carve((N_NODES + 1) * 4);
    int*   cursor    = (int*)carve(N_NODES * 4);
    int*   blocksums = (int*)carve(64 * 4);
    float2* winv     = (float2*)carve(N_NODES * 8);
    int*   csr_src   = (int*)carve(N_EDGES * 4);
    float2* csr_w    = (float2*)carve(N_EDGES * 8);
    unsigned short* XH = (unsigned short*)carve((size_t)N_NODES * 128 * 2);
    unsigned short* P1 = (unsigned short*)carve((size_t)N_NODES * 256 * 2);
    unsigned short* P2 = (unsigned short*)carve((size_t)N_NODES * 256 * 2);
    unsigned short* HR = (unsigned short*)carve((size_t)N_NODES * 64 * 2);
    unsigned short* Q1 = (unsigned short*)carve((size_t)N_NODES * 128 * 2);
    unsigned short* Q2 = (unsigned short*)carve((size_t)N_NODES * 128 * 2);
    float* Zf          = (float*)carve((size_t)N_NODES * 64 * 4);
    unsigned short* Wzr_t = (unsigned short*)carve(128 * 640 * 2);
    unsigned short* Wh_t  = (unsigned short*)carve(64 * 640 * 2);

    hipMemsetAsync(deg_out, 0, rup(N_NODES * 4) + rup(N_NODES * 4), stream);
    count_deg<<<(N_EDGES + 255) / 256, 256, 0, stream>>>(row, col, deg_out, deg_in, N_EDGES);

    int nblk = (N_NODES + 1023) / 1024;
    scan_block<<<nblk, 1024, 0, stream>>>(deg_in, rowptr, blocksums, N_NODES);
    scan_sums<<<1, 64, 0, stream>>>(blocksums, nblk);
    scan_add<<<(N_NODES + 1 + 255) / 256, 256, 0, stream>>>(rowptr, blocksums, cursor,
                                                            deg_out, deg_in, winv, N_NODES, N_EDGES);

    build_csr<<<(N_EDGES + 255) / 256, 256, 0, stream>>>(row, col, winv, cursor,
                                                         csr_src, csr_w, N_EDGES);

    pack_weights<<<(128 * 640 + 64 * 640 + 255) / 256, 256, 0, stream>>>(Wz, Wr, Wh, Wzr_t, Wh_t);

    concat_xh<<<(N_NODES * C_DIM + 255) / 256, 256, 0, stream>>>(X, H, XH, N_NODES);

    // props on XH: 2 nodes/wave
    int blocks_p128 = (((N_NODES + 1) / 2) * 64 + 255) / 256;
    prop1_128<<<blocks_p128, 256, 0, stream>>>(XH, rowptr, csr_src, csr_w, P1, N_NODES);
    prop2_128<<<blocks_p128, 256, 0, stream>>>(P1, XH, rowptr, csr_src, csr_w, P2, N_NODES);

    // Z|R GEMM -> Zf, HR
    int gemm_blocks = (N_NODES + 63) / 64;
    gemm_zr_mfma<<<gemm_blocks, 256, 0, stream>>>(XH, P1, P2, Wzr_t, bz, br, H, Zf, HR, N_NODES);

    // props on HR: 4 nodes/wave
    int blocks_p64 = (((N_NODES + 3) / 4) * 64 + 255) / 256;
    prop1_64<<<blocks_p64, 256, 0, stream>>>(HR, rowptr, csr_src, csr_w, Q1, N_NODES);
    prop2_64<<<blocks_p64, 256, 0, stream>>>(Q1, HR, rowptr, csr_src, csr_w, Q2, N_NODES);

    // H~ GEMM + GRU mix -> out
    gemm_h_mfma<<<gemm_blocks, 256, 0, stream>>>(XH, P1, P2, HR, Q1, Q2,
                                                 Wh_t, bh, Zf, H, out, N_NODES);
}